// Round 3
// baseline (43123.407 us; speedup 1.0000x reference)
//
#include <hip/hip_runtime.h>
#include <hip/hip_bf16.h>
#include <hip/hip_cooperative_groups.h>

namespace cg = cooperative_groups;
typedef __hip_bfloat16 bf16;

#define NB 64
#define NS 256
#define ND 512
#define NHE 512
#define NHD 1024
#define NGE 1536
#define NGD 3072

static __device__ __forceinline__ float sigmf(float x){ return 1.0f/(1.0f+__expf(-x)); }

// ---------------- small prep kernels ----------------
__global__ __launch_bounds__(256) void k_sx(const float* __restrict__ x,
                                            const float* __restrict__ attnW,
                                            const float* __restrict__ attnb,
                                            float* __restrict__ sx){
    int row = blockIdx.x*4 + (threadIdx.x>>6);     // row = b*256+t
    int lane = threadIdx.x & 63;
    float s = 0.f;
    for (int d = lane; d < ND; d += 64) s += x[(size_t)row*ND + d]*attnW[d];
    #pragma unroll
    for (int off = 32; off; off >>= 1) s += __shfl_down(s, off, 64);
    if (lane == 0) sx[row] = s + attnb[0];
}

__global__ __launch_bounds__(256) void k_cvec(const float* __restrict__ dWih,
                                              const float* __restrict__ linb,
                                              const float* __restrict__ dbih,
                                              float* __restrict__ cvec){
    int row = blockIdx.x*4 + (threadIdx.x>>6);     // 0..3071
    int lane = threadIdx.x & 63;
    float s = 0.f;
    for (int d = lane; d < ND; d += 64) s += dWih[(size_t)row*ND + d]*linb[d];
    #pragma unroll
    for (int off = 32; off; off >>= 1) s += __shfl_down(s, off, 64);
    if (lane == 0) cvec[row] = s + dbih[row];
}

// e stored transposed: esb[s][b]
__global__ __launch_bounds__(256) void k_softprep2(const float* __restrict__ sx,
                                                   float* __restrict__ esb,
                                                   float* __restrict__ Se){
    int b = blockIdx.x, s = threadIdx.x;
    __shared__ float red[256];
    float v = sx[b*NS + s];
    red[s] = v; __syncthreads();
    for (int off = 128; off; off >>= 1){ if (s < off) red[s] = fmaxf(red[s], red[s+off]); __syncthreads(); }
    float mx = red[0]; __syncthreads();
    float ev = __expf(v - mx);
    esb[s*NB + b] = ev;
    red[s] = ev; __syncthreads();
    for (int off = 128; off; off >>= 1){ if (s < off) red[s] += red[s+off]; __syncthreads(); }
    if (s == 0) Se[b] = red[0];
}

// z[t][h][b] = mu + eps*exp(0.5*lv); mu/lv read from hh[dir][t][j][b]
__global__ __launch_bounds__(256) void k_zexp2(const float* __restrict__ hh,
                                               const float* __restrict__ eps,
                                               bf16* __restrict__ z){
    int t  = blockIdx.x >> 4;
    int hb = blockIdx.x & 15;
    int h0 = hb*64;
    __shared__ float ls[64*69];
    int tid = threadIdx.x;
    #pragma unroll
    for (int q = 0; q < 16; ++q){
        int bb = q*4 + (tid>>6);
        int hc = tid & 63;
        ls[bb*69 + hc] = eps[((size_t)bb*NS + t)*NHD + h0 + hc];
    }
    __syncthreads();
    int b = tid & 63;
    #pragma unroll
    for (int q = 0; q < 16; ++q){
        int hq = q*4 + (tid>>6);
        int h = h0 + hq;
        int dmu = h >> 9;
        int jm  = h & 511;
        float mu = hh[(((size_t)(dmu*NS) + t)*NHE + jm)*NB + b];
        float lv = hh[(((size_t)((2+dmu)*NS) + t)*NHE + jm)*NB + b];
        float ep = ls[b*69 + hq];
        float zv = mu + ep*__expf(0.5f*lv);
        z[((size_t)t*NHD + h)*NB + b] = __float2bfloat16(zv);
    }
}

// T[h][b] = sum_s esb[s][b]*z[s][h][b]
__global__ __launch_bounds__(256) void k_T2(const bf16* __restrict__ z,
                                            const float* __restrict__ esb,
                                            float* __restrict__ T){
    int h = blockIdx.x;
    int b = threadIdx.x & 63;
    int sq = threadIdx.x >> 6;
    __shared__ float red[4][64];
    float acc = 0.f;
    #pragma unroll 8
    for (int s = sq*64; s < sq*64 + 64; ++s)
        acc += esb[s*NB + b]*__bfloat162float(z[((size_t)s*NHD + h)*NB + b]);
    red[sq][b] = acc; __syncthreads();
    if (sq == 0) T[h*NB + b] = red[0][b] + red[1][b] + red[2][b] + red[3][b];
}

// ctxT[i][h][b] = (T - e_i*z_i)/(Se - e_i)
__global__ __launch_bounds__(256) void k_ctx2(const bf16* __restrict__ z,
                                              const float* __restrict__ esb,
                                              const float* __restrict__ Se,
                                              const float* __restrict__ T,
                                              bf16* __restrict__ ctxT){
    int i  = blockIdx.x >> 4;
    int hb = blockIdx.x & 15;
    int b  = threadIdx.x & 63;
    float ei  = esb[i*NB + b];
    float inv = 1.0f/(Se[b] - ei);
    #pragma unroll
    for (int q = 0; q < 16; ++q){
        int h = hb*64 + q*4 + (threadIdx.x>>6);
        float zv = __bfloat162float(z[((size_t)i*NHD + h)*NB + b]);
        float cv = (T[h*NB + b] - ei*zv)*inv;
        ctxT[((size_t)i*NHD + h)*NB + b] = __float2bfloat16(cv);
    }
}

// mu/logvar final layout: out[b][t][1024] from hh[dir][t][j][b]
__global__ __launch_bounds__(256) void k_outT(const float* __restrict__ hh,
                                              float* __restrict__ outMu,
                                              float* __restrict__ outLv){
    int bx = blockIdx.x;
    int dir = bx >> 11;
    int t  = (bx >> 3) & 255;
    int jb = bx & 7;
    int j0 = jb*64;
    __shared__ float ls[64*65];
    int tid = threadIdx.x;
    #pragma unroll
    for (int q = 0; q < 16; ++q){
        int jj = q*4 + (tid>>6);
        ls[jj*65 + (tid&63)] = hh[(((size_t)dir*NS + t)*NHE + j0 + jj)*NB + (tid&63)];
    }
    __syncthreads();
    float* outp = (dir < 2) ? outMu : outLv;
    int colbase = (dir & 1)*512;
    #pragma unroll
    for (int q = 0; q < 16; ++q){
        int bb = q*4 + (tid>>6);
        int jj = tid & 63;
        outp[((size_t)bb*NS + t)*NHD + colbase + j0 + jj] = ls[jj*65 + bb];
    }
}

// ---------------- GEMM kernels (fp32 VALU, 64x64 tiles, 4x4/thread) ----------------
__global__ __launch_bounds__(256) void k_gemm_xg(
    const float* __restrict__ x,
    const float* __restrict__ W0, const float* __restrict__ W1,
    const float* __restrict__ W2, const float* __restrict__ W3,
    const float* __restrict__ b0, const float* __restrict__ b1,
    const float* __restrict__ b2, const float* __restrict__ b3,
    bf16* __restrict__ Xg){
    int t = blockIdx.x;
    int g0 = blockIdx.y*64;
    int dir = blockIdx.z;
    const float* W   = dir==0?W0:dir==1?W1:dir==2?W2:W3;
    const float* bih = dir==0?b0:dir==1?b1:dir==2?b2:b3;
    __shared__ float As[64][36];
    __shared__ float Bs[64][36];
    int tid = threadIdx.x, tx = tid & 15, ty = tid >> 4;
    float acc[4][4] = {};
    for (int k0 = 0; k0 < ND; k0 += 32){
        #pragma unroll
        for (int m = 0; m < 8; ++m){
            int idx = m*256 + tid;
            int row = idx >> 5, kk = idx & 31;
            As[row][kk] = x[((size_t)row*NS + t)*ND + k0 + kk];
            Bs[row][kk] = W[(size_t)(g0+row)*ND + k0 + kk];
        }
        __syncthreads();
        #pragma unroll
        for (int k4 = 0; k4 < 8; ++k4){
            float4 a[4], bb[4];
            #pragma unroll
            for (int i = 0; i < 4; ++i) a[i]  = *(const float4*)&As[ty*4+i][k4*4];
            #pragma unroll
            for (int j = 0; j < 4; ++j) bb[j] = *(const float4*)&Bs[tx*4+j][k4*4];
            #pragma unroll
            for (int i = 0; i < 4; ++i)
                #pragma unroll
                for (int j = 0; j < 4; ++j)
                    acc[i][j] += a[i].x*bb[j].x + a[i].y*bb[j].y + a[i].z*bb[j].z + a[i].w*bb[j].w;
        }
        __syncthreads();
    }
    size_t base = ((size_t)(dir*NS + t)*NGE + g0)*NB;
    #pragma unroll
    for (int j = 0; j < 4; ++j){
        float bi = bih[g0 + tx*4 + j];
        #pragma unroll
        for (int i = 0; i < 4; ++i)
            Xg[base + (size_t)(tx*4+j)*NB + ty*4 + i] = __float2bfloat16(acc[i][j] + bi);
    }
}

__global__ __launch_bounds__(256) void k_gemm_gctx(
    const bf16* __restrict__ ctxT,
    const float* __restrict__ Whh,
    const float* __restrict__ bhh,
    bf16* __restrict__ Gctx){
    int i = blockIdx.x;
    int g0 = blockIdx.y*64;
    __shared__ float As[64][36];   // [b][k]
    __shared__ float Bs[64][36];   // [g][k]
    int tid = threadIdx.x, tx = tid & 15, ty = tid >> 4;
    float acc[4][4] = {};
    for (int k0 = 0; k0 < NHD; k0 += 32){
        #pragma unroll
        for (int m = 0; m < 8; ++m){
            int idx = m*256 + tid;
            int bb2 = idx & 63, kk = idx >> 6;
            As[bb2][kk] = __bfloat162float(ctxT[((size_t)i*NHD + k0 + kk)*NB + bb2]);
            int row = idx >> 5, k2 = idx & 31;
            Bs[row][k2] = Whh[(size_t)(g0+row)*NHD + k0 + k2];
        }
        __syncthreads();
        #pragma unroll
        for (int k4 = 0; k4 < 8; ++k4){
            float4 a[4], bb[4];
            #pragma unroll
            for (int i2 = 0; i2 < 4; ++i2) a[i2]  = *(const float4*)&As[ty*4+i2][k4*4];
            #pragma unroll
            for (int j = 0; j < 4; ++j)   bb[j] = *(const float4*)&Bs[tx*4+j][k4*4];
            #pragma unroll
            for (int i2 = 0; i2 < 4; ++i2)
                #pragma unroll
                for (int j = 0; j < 4; ++j)
                    acc[i2][j] += a[i2].x*bb[j].x + a[i2].y*bb[j].y + a[i2].z*bb[j].z + a[i2].w*bb[j].w;
        }
        __syncthreads();
    }
    size_t base = ((size_t)i*NGD + g0)*NB;
    #pragma unroll
    for (int j = 0; j < 4; ++j){
        float bi = bhh[g0 + tx*4 + j];
        #pragma unroll
        for (int i2 = 0; i2 < 4; ++i2)
            Gctx[base + (size_t)(tx*4+j)*NB + ty*4 + i2] = __float2bfloat16(acc[i2][j] + bi);
    }
}

__global__ __launch_bounds__(256) void k_gemm_rec(
    const float* __restrict__ H,       // [i][k][b]
    const float* __restrict__ linW,    // [512][1024]
    const float* __restrict__ linb,
    float* __restrict__ outRec){
    int i = blockIdx.x;
    int d0 = blockIdx.y*64;
    __shared__ float As[64][36];
    __shared__ float Bs[64][36];
    int tid = threadIdx.x, tx = tid & 15, ty = tid >> 4;
    float acc[4][4] = {};
    for (int k0 = 0; k0 < NHD; k0 += 32){
        #pragma unroll
        for (int m = 0; m < 8; ++m){
            int idx = m*256 + tid;
            int bb2 = idx & 63, kk = idx >> 6;
            As[bb2][kk] = H[((size_t)i*NHD + k0 + kk)*NB + bb2];
            int row = idx >> 5, k2 = idx & 31;
            Bs[row][k2] = linW[(size_t)(d0+row)*NHD + k0 + k2];
        }
        __syncthreads();
        #pragma unroll
        for (int k4 = 0; k4 < 8; ++k4){
            float4 a[4], bb[4];
            #pragma unroll
            for (int i2 = 0; i2 < 4; ++i2) a[i2]  = *(const float4*)&As[ty*4+i2][k4*4];
            #pragma unroll
            for (int j = 0; j < 4; ++j)   bb[j] = *(const float4*)&Bs[tx*4+j][k4*4];
            #pragma unroll
            for (int i2 = 0; i2 < 4; ++i2)
                #pragma unroll
                for (int j = 0; j < 4; ++j)
                    acc[i2][j] += a[i2].x*bb[j].x + a[i2].y*bb[j].y + a[i2].z*bb[j].z + a[i2].w*bb[j].w;
        }
        __syncthreads();
    }
    #pragma unroll
    for (int j = 0; j < 4; ++j){
        float lb = linb[d0 + tx*4 + j];
        #pragma unroll
        for (int i2 = 0; i2 < 4; ++i2){
            int bb2 = ty*4 + i2;
            outRec[((size_t)bb2*NS + i)*ND + d0 + tx*4 + j] = acc[i2][j] + lb;
        }
    }
}

__global__ __launch_bounds__(256) void k_gemm_M(
    const float* __restrict__ dWih,
    const float* __restrict__ linW,
    float* __restrict__ M){
    int g0 = blockIdx.x*64;
    int h0 = blockIdx.y*64;
    __shared__ float As[64][36];   // [g][k]
    __shared__ float Bs[32][68];   // [k][h]
    int tid = threadIdx.x, tx = tid & 15, ty = tid >> 4;
    float acc[4][4] = {};
    for (int k0 = 0; k0 < ND; k0 += 32){
        #pragma unroll
        for (int m = 0; m < 8; ++m){
            int idx = m*256 + tid;
            int row = idx >> 5, kk = idx & 31;
            As[row][kk] = dWih[(size_t)(g0+row)*ND + k0 + kk];
            int k2 = idx >> 6, hh2 = idx & 63;
            Bs[k2][hh2] = linW[(size_t)(k0+k2)*NHD + h0 + hh2];
        }
        __syncthreads();
        for (int k = 0; k < 32; ++k){
            float a[4];
            #pragma unroll
            for (int i = 0; i < 4; ++i) a[i] = As[ty*4+i][k];
            float4 b4 = *(const float4*)&Bs[k][tx*4];
            #pragma unroll
            for (int i = 0; i < 4; ++i){
                acc[i][0] += a[i]*b4.x; acc[i][1] += a[i]*b4.y;
                acc[i][2] += a[i]*b4.z; acc[i][3] += a[i]*b4.w;
            }
        }
        __syncthreads();
    }
    #pragma unroll
    for (int i = 0; i < 4; ++i)
        #pragma unroll
        for (int j = 0; j < 4; ++j)
            M[(size_t)(g0+ty*4+i)*NHD + h0 + tx*4 + j] = acc[i][j];
}

// ---------------- persistent cooperative recurrence kernels ----------------
// conflict-free staging: thread loads 4 k-consecutive dwords of h[k][b]
// (coalesced over b=lane) and does one ds_write_b128 to hs[b*132 + k].
// stride 132 == 4 (mod 32) -> lane b hits bank group 4b mod 32: minimal aliasing.

// encoder: 512 WGs = 4 dirs x 128 col-groups, 2 blocks/CU; wave owns 1 col, full K=512
__global__ __launch_bounds__(256, 2) void k_encoder3(
    const bf16* __restrict__ Xg,
    const float* __restrict__ W0, const float* __restrict__ W1,
    const float* __restrict__ W2, const float* __restrict__ W3,
    const float* __restrict__ b0, const float* __restrict__ b1,
    const float* __restrict__ b2, const float* __restrict__ b3,
    float* __restrict__ hh){   // [4][256][512][64]
    cg::grid_group grid = cg::this_grid();
    int dir = blockIdx.x & 3;
    int jg  = blockIdx.x >> 2;                      // 0..127
    int tid = threadIdx.x;
    int b   = tid & 63;
    int ks  = tid >> 6;                             // vector form (staging)
    int tc  = __builtin_amdgcn_readfirstlane(tid >> 6);  // scalar form (pointers)
    int j   = jg*4 + tc;                            // 0..511
    const float* Whh = dir==0?W0:dir==1?W1:dir==2?W2:W3;
    const float* bhh = dir==0?b0:dir==1?b1:dir==2?b2:b3;
    const float* wr = Whh + (size_t)j*NHE;
    const float* wz = Whh + (size_t)(j+512)*NHE;
    const float* wn = Whh + (size_t)(j+1024)*NHE;
    float br = bhh[j], bz = bhh[j+512], bn = bhh[j+1024];
    __shared__ float hs[64*132];
    float hpv = 0.f;
    for (int t = 0; t < NS; ++t){
        int tcur = (dir & 1) ? (255 - t) : t;
        size_t xgb = ((size_t)(dir*NS + tcur)*NGE)*NB + b;
        float gir = __bfloat162float(Xg[xgb + (size_t)j*NB]);
        float giz = __bfloat162float(Xg[xgb + (size_t)(j+512)*NB]);
        float gin = __bfloat162float(Xg[xgb + (size_t)(j+1024)*NB]);
        float a0 = 0.f, a1 = 0.f, a2 = 0.f;
        if (t > 0){
            int tprev = (dir & 1) ? (256 - t) : (t - 1);
            const float* hp = hh + ((size_t)(dir*NS + tprev)*NHE)*NB;
            for (int c = 0; c < 4; ++c){
                int cb = c*128;
                __syncthreads();
                #pragma unroll
                for (int q = 0; q < 8; ++q){
                    int kloc = q*16 + ks*4;
                    float4 v;
                    v.x = hp[(size_t)(cb+kloc+0)*NB + b];
                    v.y = hp[(size_t)(cb+kloc+1)*NB + b];
                    v.z = hp[(size_t)(cb+kloc+2)*NB + b];
                    v.w = hp[(size_t)(cb+kloc+3)*NB + b];
                    *(float4*)&hs[b*132 + kloc] = v;
                }
                __syncthreads();
                const float* hrow = &hs[b*132];
                #pragma unroll 4
                for (int kq = 0; kq < 32; ++kq){
                    float4 h4 = *(const float4*)(hrow + kq*4);
                    float4 wa = *(const float4*)(wr + cb + kq*4);
                    float4 wb = *(const float4*)(wz + cb + kq*4);
                    float4 wc = *(const float4*)(wn + cb + kq*4);
                    a0 += h4.x*wa.x + h4.y*wa.y + h4.z*wa.z + h4.w*wa.w;
                    a1 += h4.x*wb.x + h4.y*wb.y + h4.z*wb.z + h4.w*wb.w;
                    a2 += h4.x*wc.x + h4.y*wc.y + h4.z*wc.z + h4.w*wc.w;
                }
            }
        }
        float r  = sigmf(gir + a0 + br);
        float zg = sigmf(giz + a1 + bz);
        float n  = tanhf(gin + r*(a2 + bn));
        hpv = (1.0f - zg)*n + zg*hpv;
        hh[((size_t)(dir*NS + tcur)*NHE + j)*NB + b] = hpv;
        grid.sync();
    }
}

// decoder: 512 WGs, 2 blocks/CU; wave = (j = blk*2 + (tc&1), K-half = tc>>1)
__global__ __launch_bounds__(256, 2) void k_decoder3(
    const float* __restrict__ M,
    const float* __restrict__ cvec,
    const float* __restrict__ dbih,
    const bf16* __restrict__ Gctx,
    const bf16* __restrict__ ctxT,
    float* __restrict__ H){
    cg::grid_group grid = cg::this_grid();
    int tid = threadIdx.x;
    int b   = tid & 63;
    int ks  = tid >> 6;
    int tc  = __builtin_amdgcn_readfirstlane(tid >> 6);
    int u   = tc & 1;          // which j of the pair
    int kh  = tc >> 1;         // K-half
    int j   = blockIdx.x*2 + u;     // 0..1023
    const float* m0 = M + (size_t)j*NHD;
    const float* m1 = M + (size_t)(j+NHD)*NHD;
    const float* m2 = M + (size_t)(j+2*NHD)*NHD;
    float c0 = cvec[j], c1 = cvec[j+NHD], c2 = cvec[j+2*NHD];
    float d0 = dbih[j], d1 = dbih[j+NHD], d2 = dbih[j+2*NHD];
    __shared__ float hs[64*132];
    __shared__ float red[2][3][64];
    for (int i = 0; i < NS; ++i){
        float g0, g1, g2;
        if (i == 0){ g0 = d0; g1 = d1; g2 = d2; }
        else {
            const float* hp = H + (size_t)(i-1)*NHD*NB;
            float a0 = 0.f, a1 = 0.f, a2 = 0.f;
            for (int c = 0; c < 8; ++c){
                int cb = c*128;
                __syncthreads();
                #pragma unroll
                for (int q = 0; q < 8; ++q){
                    int kloc = q*16 + ks*4;
                    float4 v;
                    v.x = hp[(size_t)(cb+kloc+0)*NB + b];
                    v.y = hp[(size_t)(cb+kloc+1)*NB + b];
                    v.z = hp[(size_t)(cb+kloc+2)*NB + b];
                    v.w = hp[(size_t)(cb+kloc+3)*NB + b];
                    *(float4*)&hs[b*132 + kloc] = v;
                }
                __syncthreads();
                if ((c >> 2) == kh){
                    const float* hrow = &hs[b*132];
                    #pragma unroll 4
                    for (int kq = 0; kq < 32; ++kq){
                        float4 h4 = *(const float4*)(hrow + kq*4);
                        float4 wa = *(const float4*)(m0 + cb + kq*4);
                        float4 wb = *(const float4*)(m1 + cb + kq*4);
                        float4 wc = *(const float4*)(m2 + cb + kq*4);
                        a0 += h4.x*wa.x + h4.y*wa.y + h4.z*wa.z + h4.w*wa.w;
                        a1 += h4.x*wb.x + h4.y*wb.y + h4.z*wb.z + h4.w*wb.w;
                        a2 += h4.x*wc.x + h4.y*wc.y + h4.z*wc.z + h4.w*wc.w;
                    }
                }
            }
            if (kh == 1){
                red[u][0][b] = a0; red[u][1][b] = a1; red[u][2][b] = a2;
            }
            __syncthreads();
            if (kh == 0){
                a0 += red[u][0][b]; a1 += red[u][1][b]; a2 += red[u][2][b];
            }
            g0 = a0 + c0; g1 = a1 + c1; g2 = a2 + c2;
        }
        if (kh == 0){
            size_t gb = (size_t)i*NGD*NB + b;
            float ghr = __bfloat162float(Gctx[gb + (size_t)j*NB]);
            float ghz = __bfloat162float(Gctx[gb + (size_t)(j+NHD)*NB]);
            float ghn = __bfloat162float(Gctx[gb + (size_t)(j+2*NHD)*NB]);
            float cv  = __bfloat162float(ctxT[((size_t)i*NHD + j)*NB + b]);
            float r  = sigmf(g0 + ghr);
            float zg = sigmf(g1 + ghz);
            float n  = tanhf(g2 + r*ghn);
            float hn = (1.0f - zg)*n + zg*cv;
            H[((size_t)i*NHD + j)*NB + b] = hn;
        }
        grid.sync();
    }
}

// ---------------- host launcher ----------------
extern "C" void kernel_launch(void* const* d_in, const int* in_sizes, int n_in,
                              void* d_out, int out_size, void* d_ws, size_t ws_size,
                              hipStream_t stream){
    const float* x   = (const float*)d_in[0];
    const float* eps = (const float*)d_in[1];
    const float* Wih[4]; const float* Whh[4]; const float* bih[4]; const float* bhh[4];
    for (int d = 0; d < 4; ++d){
        Wih[d] = (const float*)d_in[2 + 4*d];
        Whh[d] = (const float*)d_in[3 + 4*d];
        bih[d] = (const float*)d_in[4 + 4*d];
        bhh[d] = (const float*)d_in[5 + 4*d];
    }
    const float* dWih  = (const float*)d_in[18];
    const float* dWhh  = (const float*)d_in[19];
    const float* dbih  = (const float*)d_in[20];
    const float* dbhh  = (const float*)d_in[21];
    const float* attnW = (const float*)d_in[22];
    const float* attnb = (const float*)d_in[23];
    const float* linW  = (const float*)d_in[24];
    const float* linb  = (const float*)d_in[25];

    float* out    = (float*)d_out;
    float* outRec = out;
    float* outMu  = out + 8388608;
    float* outLv  = out + 25165824;

    char* ws = (char*)d_ws;
    bf16*  Xg    = (bf16*)(ws + 0);              // 201326592   (dead after encoder)
    bf16*  Gctx  = (bf16*)(ws + 0);              // 100663296   (reuses Xg space)
    float* Hdec  = (float*)(ws + 100663296);     // 67108864    (reuses Xg space)
    float* hh    = (float*)(ws + 201326592);     // 134217728
    bf16*  zbuf  = (bf16*)(ws + 335544320);      // 33554432
    bf16*  ctxT  = (bf16*)(ws + 369098752);      // 33554432
    float* Mbuf  = (float*)(ws + 402653184);     // 12582912
    float* sx    = (float*)(ws + 415236096);     // 65536
    float* esb   = (float*)(ws + 415301632);     // 65536
    float* Se    = (float*)(ws + 415367168);     // 4096
    float* Tbuf  = (float*)(ws + 415371264);     // 262144
    float* cvec  = (float*)(ws + 415633408);     // 12288

    // phase 0: parallel prep
    hipLaunchKernelGGL(k_gemm_M, dim3(48,16), dim3(256), 0, stream, dWih, linW, Mbuf);
    hipLaunchKernelGGL(k_cvec, dim3(768), dim3(256), 0, stream, dWih, linb, dbih, cvec);
    hipLaunchKernelGGL(k_sx, dim3(4096), dim3(256), 0, stream, x, attnW, attnb, sx);
    hipLaunchKernelGGL(k_softprep2, dim3(64), dim3(256), 0, stream, sx, esb, Se);
    hipLaunchKernelGGL(k_gemm_xg, dim3(256,24,4), dim3(256), 0, stream,
                       x, Wih[0], Wih[1], Wih[2], Wih[3], bih[0], bih[1], bih[2], bih[3], Xg);

    // phase 1: encoder recurrence -> hh
    {
        void* a[] = { (void*)&Xg, (void*)&Whh[0], (void*)&Whh[1], (void*)&Whh[2], (void*)&Whh[3],
                      (void*)&bhh[0], (void*)&bhh[1], (void*)&bhh[2], (void*)&bhh[3], (void*)&hh };
        hipLaunchCooperativeKernel((void*)k_encoder3, dim3(512), dim3(256), a, 0, stream);
    }

    // phase 2: z, attention statics, Gctx; mu/logvar output transpose
    hipLaunchKernelGGL(k_zexp2, dim3(4096), dim3(256), 0, stream, hh, eps, zbuf);
    hipLaunchKernelGGL(k_outT, dim3(8192), dim3(256), 0, stream, hh, outMu, outLv);
    hipLaunchKernelGGL(k_T2, dim3(1024), dim3(256), 0, stream, zbuf, esb, Tbuf);
    hipLaunchKernelGGL(k_ctx2, dim3(4096), dim3(256), 0, stream, zbuf, esb, Se, Tbuf, ctxT);
    hipLaunchKernelGGL(k_gemm_gctx, dim3(256,48), dim3(256), 0, stream, ctxT, dWhh, dbhh, Gctx);

    // phase 3: decoder recurrence
    {
        void* a[] = { (void*)&Mbuf, (void*)&cvec, (void*)&dbih, (void*)&Gctx, (void*)&ctxT, (void*)&Hdec };
        hipLaunchCooperativeKernel((void*)k_decoder3, dim3(512), dim3(256), a, 0, stream);
    }

    // phase 4: output projection
    hipLaunchKernelGGL(k_gemm_rec, dim3(256,8), dim3(256), 0, stream, Hdec, linW, linb, outRec);
}

// Round 4
// 24096.014 us; speedup vs baseline: 1.7896x; 1.7896x over previous
//
#include <hip/hip_runtime.h>
#include <hip/hip_bf16.h>
#include <hip/hip_cooperative_groups.h>

namespace cg = cooperative_groups;
typedef __hip_bfloat16 bf16;

#define NB 64
#define NS 256
#define ND 512
#define NHE 512
#define NHD 1024
#define NGE 1536
#define NGD 3072

static __device__ __forceinline__ float sigmf(float x){ return 1.0f/(1.0f+__expf(-x)); }

// ---- custom grid barrier: 16 leaves -> root -> epoch flag ----
// bar layout (uint): leaf[g] at bar[g*32] (g=0..15), root at bar[512], flag at bar[544]
static __device__ __forceinline__ void gridbar(unsigned int* bar, int step, int nper){
    __syncthreads();
    if (threadIdx.x == 0){
        __threadfence();   // release: drain stores + L2 writeback
        int g = blockIdx.x & 15;
        unsigned int old = __hip_atomic_fetch_add(bar + g*32, 1u, __ATOMIC_RELAXED, __HIP_MEMORY_SCOPE_AGENT);
        if ((old & (unsigned)(nper-1)) == (unsigned)(nper-1)){
            unsigned int r = __hip_atomic_fetch_add(bar + 512, 1u, __ATOMIC_RELAXED, __HIP_MEMORY_SCOPE_AGENT);
            if ((r & 15u) == 15u)
                __hip_atomic_store(bar + 544, (unsigned int)step, __ATOMIC_RELEASE, __HIP_MEMORY_SCOPE_AGENT);
        }
        while ((int)__hip_atomic_load(bar + 544, __ATOMIC_RELAXED, __HIP_MEMORY_SCOPE_AGENT) < step)
            __builtin_amdgcn_s_sleep(8);
        __threadfence();   // acquire: invalidate stale L1/L2
    }
    __syncthreads();
}

// ---------------- small prep kernels ----------------
__global__ __launch_bounds__(256) void k_sx(const float* __restrict__ x,
                                            const float* __restrict__ attnW,
                                            const float* __restrict__ attnb,
                                            float* __restrict__ sx){
    int row = blockIdx.x*4 + (threadIdx.x>>6);     // row = b*256+t
    int lane = threadIdx.x & 63;
    float s = 0.f;
    for (int d = lane; d < ND; d += 64) s += x[(size_t)row*ND + d]*attnW[d];
    #pragma unroll
    for (int off = 32; off; off >>= 1) s += __shfl_down(s, off, 64);
    if (lane == 0) sx[row] = s + attnb[0];
}

__global__ __launch_bounds__(256) void k_cvec(const float* __restrict__ dWih,
                                              const float* __restrict__ linb,
                                              const float* __restrict__ dbih,
                                              float* __restrict__ cvec){
    int row = blockIdx.x*4 + (threadIdx.x>>6);     // 0..3071
    int lane = threadIdx.x & 63;
    float s = 0.f;
    for (int d = lane; d < ND; d += 64) s += dWih[(size_t)row*ND + d]*linb[d];
    #pragma unroll
    for (int off = 32; off; off >>= 1) s += __shfl_down(s, off, 64);
    if (lane == 0) cvec[row] = s + dbih[row];
}

// e stored transposed: esb[s][b]
__global__ __launch_bounds__(256) void k_softprep2(const float* __restrict__ sx,
                                                   float* __restrict__ esb,
                                                   float* __restrict__ Se){
    int b = blockIdx.x, s = threadIdx.x;
    __shared__ float red[256];
    float v = sx[b*NS + s];
    red[s] = v; __syncthreads();
    for (int off = 128; off; off >>= 1){ if (s < off) red[s] = fmaxf(red[s], red[s+off]); __syncthreads(); }
    float mx = red[0]; __syncthreads();
    float ev = __expf(v - mx);
    esb[s*NB + b] = ev;
    red[s] = ev; __syncthreads();
    for (int off = 128; off; off >>= 1){ if (s < off) red[s] += red[s+off]; __syncthreads(); }
    if (s == 0) Se[b] = red[0];
}

// z[t][h][b] = mu + eps*exp(0.5*lv); mu/lv read from hh[dir][t][j][b]
__global__ __launch_bounds__(256) void k_zexp2(const float* __restrict__ hh,
                                               const float* __restrict__ eps,
                                               bf16* __restrict__ z){
    int t  = blockIdx.x >> 4;
    int hb = blockIdx.x & 15;
    int h0 = hb*64;
    __shared__ float ls[64*69];
    int tid = threadIdx.x;
    #pragma unroll
    for (int q = 0; q < 16; ++q){
        int bb = q*4 + (tid>>6);
        int hc = tid & 63;
        ls[bb*69 + hc] = eps[((size_t)bb*NS + t)*NHD + h0 + hc];
    }
    __syncthreads();
    int b = tid & 63;
    #pragma unroll
    for (int q = 0; q < 16; ++q){
        int hq = q*4 + (tid>>6);
        int h = h0 + hq;
        int dmu = h >> 9;
        int jm  = h & 511;
        float mu = hh[(((size_t)(dmu*NS) + t)*NHE + jm)*NB + b];
        float lv = hh[(((size_t)((2+dmu)*NS) + t)*NHE + jm)*NB + b];
        float ep = ls[b*69 + hq];
        float zv = mu + ep*__expf(0.5f*lv);
        z[((size_t)t*NHD + h)*NB + b] = __float2bfloat16(zv);
    }
}

// T[h][b] = sum_s esb[s][b]*z[s][h][b]
__global__ __launch_bounds__(256) void k_T2(const bf16* __restrict__ z,
                                            const float* __restrict__ esb,
                                            float* __restrict__ T){
    int h = blockIdx.x;
    int b = threadIdx.x & 63;
    int sq = threadIdx.x >> 6;
    __shared__ float red[4][64];
    float acc = 0.f;
    #pragma unroll 8
    for (int s = sq*64; s < sq*64 + 64; ++s)
        acc += esb[s*NB + b]*__bfloat162float(z[((size_t)s*NHD + h)*NB + b]);
    red[sq][b] = acc; __syncthreads();
    if (sq == 0) T[h*NB + b] = red[0][b] + red[1][b] + red[2][b] + red[3][b];
}

// ctxT[i][h][b] = (T - e_i*z_i)/(Se - e_i)
__global__ __launch_bounds__(256) void k_ctx2(const bf16* __restrict__ z,
                                              const float* __restrict__ esb,
                                              const float* __restrict__ Se,
                                              const float* __restrict__ T,
                                              bf16* __restrict__ ctxT){
    int i  = blockIdx.x >> 4;
    int hb = blockIdx.x & 15;
    int b  = threadIdx.x & 63;
    float ei  = esb[i*NB + b];
    float inv = 1.0f/(Se[b] - ei);
    #pragma unroll
    for (int q = 0; q < 16; ++q){
        int h = hb*64 + q*4 + (threadIdx.x>>6);
        float zv = __bfloat162float(z[((size_t)i*NHD + h)*NB + b]);
        float cv = (T[h*NB + b] - ei*zv)*inv;
        ctxT[((size_t)i*NHD + h)*NB + b] = __float2bfloat16(cv);
    }
}

// mu/logvar final layout: out[b][t][1024] from hh[dir][t][j][b]
__global__ __launch_bounds__(256) void k_outT(const float* __restrict__ hh,
                                              float* __restrict__ outMu,
                                              float* __restrict__ outLv){
    int bx = blockIdx.x;
    int dir = bx >> 11;
    int t  = (bx >> 3) & 255;
    int jb = bx & 7;
    int j0 = jb*64;
    __shared__ float ls[64*65];
    int tid = threadIdx.x;
    #pragma unroll
    for (int q = 0; q < 16; ++q){
        int jj = q*4 + (tid>>6);
        ls[jj*65 + (tid&63)] = hh[(((size_t)dir*NS + t)*NHE + j0 + jj)*NB + (tid&63)];
    }
    __syncthreads();
    float* outp = (dir < 2) ? outMu : outLv;
    int colbase = (dir & 1)*512;
    #pragma unroll
    for (int q = 0; q < 16; ++q){
        int bb = q*4 + (tid>>6);
        int jj = tid & 63;
        outp[((size_t)bb*NS + t)*NHD + colbase + j0 + jj] = ls[jj*65 + bb];
    }
}

// ---------------- GEMM kernels (fp32 VALU, 64x64 tiles, 4x4/thread) ----------------
__global__ __launch_bounds__(256) void k_gemm_xg(
    const float* __restrict__ x,
    const float* __restrict__ W0, const float* __restrict__ W1,
    const float* __restrict__ W2, const float* __restrict__ W3,
    const float* __restrict__ b0, const float* __restrict__ b1,
    const float* __restrict__ b2, const float* __restrict__ b3,
    bf16* __restrict__ Xg){
    int t = blockIdx.x;
    int g0 = blockIdx.y*64;
    int dir = blockIdx.z;
    const float* W   = dir==0?W0:dir==1?W1:dir==2?W2:W3;
    const float* bih = dir==0?b0:dir==1?b1:dir==2?b2:b3;
    __shared__ float As[64][36];
    __shared__ float Bs[64][36];
    int tid = threadIdx.x, tx = tid & 15, ty = tid >> 4;
    float acc[4][4] = {};
    for (int k0 = 0; k0 < ND; k0 += 32){
        #pragma unroll
        for (int m = 0; m < 8; ++m){
            int idx = m*256 + tid;
            int row = idx >> 5, kk = idx & 31;
            As[row][kk] = x[((size_t)row*NS + t)*ND + k0 + kk];
            Bs[row][kk] = W[(size_t)(g0+row)*ND + k0 + kk];
        }
        __syncthreads();
        #pragma unroll
        for (int k4 = 0; k4 < 8; ++k4){
            float4 a[4], bb[4];
            #pragma unroll
            for (int i = 0; i < 4; ++i) a[i]  = *(const float4*)&As[ty*4+i][k4*4];
            #pragma unroll
            for (int j = 0; j < 4; ++j) bb[j] = *(const float4*)&Bs[tx*4+j][k4*4];
            #pragma unroll
            for (int i = 0; i < 4; ++i)
                #pragma unroll
                for (int j = 0; j < 4; ++j)
                    acc[i][j] += a[i].x*bb[j].x + a[i].y*bb[j].y + a[i].z*bb[j].z + a[i].w*bb[j].w;
        }
        __syncthreads();
    }
    size_t base = ((size_t)(dir*NS + t)*NGE + g0)*NB;
    #pragma unroll
    for (int j = 0; j < 4; ++j){
        float bi = bih[g0 + tx*4 + j];
        #pragma unroll
        for (int i = 0; i < 4; ++i)
            Xg[base + (size_t)(tx*4+j)*NB + ty*4 + i] = __float2bfloat16(acc[i][j] + bi);
    }
}

__global__ __launch_bounds__(256) void k_gemm_gctx(
    const bf16* __restrict__ ctxT,
    const float* __restrict__ Whh,
    const float* __restrict__ bhh,
    bf16* __restrict__ Gctx){
    int i = blockIdx.x;
    int g0 = blockIdx.y*64;
    __shared__ float As[64][36];   // [b][k]
    __shared__ float Bs[64][36];   // [g][k]
    int tid = threadIdx.x, tx = tid & 15, ty = tid >> 4;
    float acc[4][4] = {};
    for (int k0 = 0; k0 < NHD; k0 += 32){
        #pragma unroll
        for (int m = 0; m < 8; ++m){
            int idx = m*256 + tid;
            int bb2 = idx & 63, kk = idx >> 6;
            As[bb2][kk] = __bfloat162float(ctxT[((size_t)i*NHD + k0 + kk)*NB + bb2]);
            int row = idx >> 5, k2 = idx & 31;
            Bs[row][k2] = Whh[(size_t)(g0+row)*NHD + k0 + k2];
        }
        __syncthreads();
        #pragma unroll
        for (int k4 = 0; k4 < 8; ++k4){
            float4 a[4], bb[4];
            #pragma unroll
            for (int i2 = 0; i2 < 4; ++i2) a[i2]  = *(const float4*)&As[ty*4+i2][k4*4];
            #pragma unroll
            for (int j = 0; j < 4; ++j)   bb[j] = *(const float4*)&Bs[tx*4+j][k4*4];
            #pragma unroll
            for (int i2 = 0; i2 < 4; ++i2)
                #pragma unroll
                for (int j = 0; j < 4; ++j)
                    acc[i2][j] += a[i2].x*bb[j].x + a[i2].y*bb[j].y + a[i2].z*bb[j].z + a[i2].w*bb[j].w;
        }
        __syncthreads();
    }
    size_t base = ((size_t)i*NGD + g0)*NB;
    #pragma unroll
    for (int j = 0; j < 4; ++j){
        float bi = bhh[g0 + tx*4 + j];
        #pragma unroll
        for (int i2 = 0; i2 < 4; ++i2)
            Gctx[base + (size_t)(tx*4+j)*NB + ty*4 + i2] = __float2bfloat16(acc[i2][j] + bi);
    }
}

__global__ __launch_bounds__(256) void k_gemm_rec(
    const float* __restrict__ H,       // [i][k][b]
    const float* __restrict__ linW,    // [512][1024]
    const float* __restrict__ linb,
    float* __restrict__ outRec){
    int i = blockIdx.x;
    int d0 = blockIdx.y*64;
    __shared__ float As[64][36];
    __shared__ float Bs[64][36];
    int tid = threadIdx.x, tx = tid & 15, ty = tid >> 4;
    float acc[4][4] = {};
    for (int k0 = 0; k0 < NHD; k0 += 32){
        #pragma unroll
        for (int m = 0; m < 8; ++m){
            int idx = m*256 + tid;
            int bb2 = idx & 63, kk = idx >> 6;
            As[bb2][kk] = H[((size_t)i*NHD + k0 + kk)*NB + bb2];
            int row = idx >> 5, k2 = idx & 31;
            Bs[row][k2] = linW[(size_t)(d0+row)*NHD + k0 + k2];
        }
        __syncthreads();
        #pragma unroll
        for (int k4 = 0; k4 < 8; ++k4){
            float4 a[4], bb[4];
            #pragma unroll
            for (int i2 = 0; i2 < 4; ++i2) a[i2]  = *(const float4*)&As[ty*4+i2][k4*4];
            #pragma unroll
            for (int j = 0; j < 4; ++j)   bb[j] = *(const float4*)&Bs[tx*4+j][k4*4];
            #pragma unroll
            for (int i2 = 0; i2 < 4; ++i2)
                #pragma unroll
                for (int j = 0; j < 4; ++j)
                    acc[i2][j] += a[i2].x*bb[j].x + a[i2].y*bb[j].y + a[i2].z*bb[j].z + a[i2].w*bb[j].w;
        }
        __syncthreads();
    }
    #pragma unroll
    for (int j = 0; j < 4; ++j){
        float lb = linb[d0 + tx*4 + j];
        #pragma unroll
        for (int i2 = 0; i2 < 4; ++i2){
            int bb2 = ty*4 + i2;
            outRec[((size_t)bb2*NS + i)*ND + d0 + tx*4 + j] = acc[i2][j] + lb;
        }
    }
}

__global__ __launch_bounds__(256) void k_gemm_M(
    const float* __restrict__ dWih,
    const float* __restrict__ linW,
    float* __restrict__ M){
    int g0 = blockIdx.x*64;
    int h0 = blockIdx.y*64;
    __shared__ float As[64][36];   // [g][k]
    __shared__ float Bs[32][68];   // [k][h]
    int tid = threadIdx.x, tx = tid & 15, ty = tid >> 4;
    float acc[4][4] = {};
    for (int k0 = 0; k0 < ND; k0 += 32){
        #pragma unroll
        for (int m = 0; m < 8; ++m){
            int idx = m*256 + tid;
            int row = idx >> 5, kk = idx & 31;
            As[row][kk] = dWih[(size_t)(g0+row)*ND + k0 + kk];
            int k2 = idx >> 6, hh2 = idx & 63;
            Bs[k2][hh2] = linW[(size_t)(k0+k2)*NHD + h0 + hh2];
        }
        __syncthreads();
        for (int k = 0; k < 32; ++k){
            float a[4];
            #pragma unroll
            for (int i = 0; i < 4; ++i) a[i] = As[ty*4+i][k];
            float4 b4 = *(const float4*)&Bs[k][tx*4];
            #pragma unroll
            for (int i = 0; i < 4; ++i){
                acc[i][0] += a[i]*b4.x; acc[i][1] += a[i]*b4.y;
                acc[i][2] += a[i]*b4.z; acc[i][3] += a[i]*b4.w;
            }
        }
        __syncthreads();
    }
    #pragma unroll
    for (int i = 0; i < 4; ++i)
        #pragma unroll
        for (int j = 0; j < 4; ++j)
            M[(size_t)(g0+ty*4+i)*NHD + h0 + tx*4 + j] = acc[i][j];
}

// ---------------- persistent cooperative recurrence kernels ----------------
// encoder: 512 WGs = 4 dirs x 128 col-groups, 2 blocks/CU; wave owns 1 col, full K=512.
// Weights staged to LDS once (24KB/WG); h staged [k][b]->[b][k] stride-132 (conflict-free).
__global__ __launch_bounds__(256, 2) void k_encoder4(
    const bf16* __restrict__ Xg,
    const float* __restrict__ W0, const float* __restrict__ W1,
    const float* __restrict__ W2, const float* __restrict__ W3,
    const float* __restrict__ b0, const float* __restrict__ b1,
    const float* __restrict__ b2, const float* __restrict__ b3,
    float* __restrict__ hh,        // [4][256][512][64]
    unsigned int* bar){
    int dir = blockIdx.x & 3;
    int jg  = blockIdx.x >> 2;                      // 0..127
    int tid = threadIdx.x;
    int b   = tid & 63;
    int ks  = tid >> 6;                             // vector form (staging)
    int tc  = __builtin_amdgcn_readfirstlane(tid >> 6);  // scalar form
    int j   = jg*4 + tc;                            // 0..511
    const float* Whh = dir==0?W0:dir==1?W1:dir==2?W2:W3;
    const float* bhh = dir==0?b0:dir==1?b1:dir==2?b2:b3;
    float br = bhh[j], bz = bhh[j+512], bn = bhh[j+1024];
    __shared__ float wlds[4][3][512];
    __shared__ float hs[64*132];
    // stage weights: 4 cols x 3 gates x 512 = 1536 float4
    for (int q = tid; q < 1536; q += 256){
        int w = q / 384;
        int rem = q % 384;
        int p = rem / 128;
        int kk = (rem % 128)*4;
        *(float4*)&wlds[w][p][kk] = *(const float4*)&Whh[(size_t)(jg*4 + w + p*512)*NHE + kk];
    }
    __syncthreads();
    float hpv = 0.f;
    for (int t = 0; t < NS; ++t){
        int tcur = (dir & 1) ? (255 - t) : t;
        size_t xgb = ((size_t)(dir*NS + tcur)*NGE)*NB + b;
        float gir = __bfloat162float(Xg[xgb + (size_t)j*NB]);
        float giz = __bfloat162float(Xg[xgb + (size_t)(j+512)*NB]);
        float gin = __bfloat162float(Xg[xgb + (size_t)(j+1024)*NB]);
        float a0 = 0.f, a1 = 0.f, a2 = 0.f;
        if (t > 0){
            int tprev = (dir & 1) ? (256 - t) : (t - 1);
            const float* hp = hh + ((size_t)(dir*NS + tprev)*NHE)*NB;
            for (int c = 0; c < 4; ++c){
                int cb = c*128;
                __syncthreads();
                #pragma unroll
                for (int q = 0; q < 8; ++q){
                    int kloc = q*16 + ks*4;
                    float4 v;
                    v.x = hp[(size_t)(cb+kloc+0)*NB + b];
                    v.y = hp[(size_t)(cb+kloc+1)*NB + b];
                    v.z = hp[(size_t)(cb+kloc+2)*NB + b];
                    v.w = hp[(size_t)(cb+kloc+3)*NB + b];
                    *(float4*)&hs[b*132 + kloc] = v;
                }
                __syncthreads();
                const float* hrow = &hs[b*132];
                const float* wr = &wlds[tc][0][cb];
                const float* wz = &wlds[tc][1][cb];
                const float* wn = &wlds[tc][2][cb];
                #pragma unroll 4
                for (int kq = 0; kq < 32; ++kq){
                    float4 h4 = *(const float4*)(hrow + kq*4);
                    float4 wa = *(const float4*)(wr + kq*4);
                    float4 wb = *(const float4*)(wz + kq*4);
                    float4 wc = *(const float4*)(wn + kq*4);
                    a0 += h4.x*wa.x + h4.y*wa.y + h4.z*wa.z + h4.w*wa.w;
                    a1 += h4.x*wb.x + h4.y*wb.y + h4.z*wb.z + h4.w*wb.w;
                    a2 += h4.x*wc.x + h4.y*wc.y + h4.z*wc.z + h4.w*wc.w;
                }
            }
        }
        float r  = sigmf(gir + a0 + br);
        float zg = sigmf(giz + a1 + bz);
        float n  = tanhf(gin + r*(a2 + bn));
        hpv = (1.0f - zg)*n + zg*hpv;
        hh[((size_t)(dir*NS + tcur)*NHE + j)*NB + b] = hpv;
        gridbar(bar, t+1, 32);
    }
}

// decoder: 512 WGs, 2 blocks/CU; wave = (j = blk*2 + (tc&1), K-half = tc>>1); M rows in LDS
__global__ __launch_bounds__(256, 2) void k_decoder4(
    const float* __restrict__ M,
    const float* __restrict__ cvec,
    const float* __restrict__ dbih,
    const bf16* __restrict__ Gctx,
    const bf16* __restrict__ ctxT,
    float* __restrict__ H,
    unsigned int* bar){
    int tid = threadIdx.x;
    int b   = tid & 63;
    int ks  = tid >> 6;
    int tc  = __builtin_amdgcn_readfirstlane(tid >> 6);
    int u   = tc & 1;          // which j of the pair
    int kh  = tc >> 1;         // K-half
    int j   = blockIdx.x*2 + u;     // 0..1023
    float c0 = cvec[j], c1 = cvec[j+NHD], c2 = cvec[j+2*NHD];
    float d0 = dbih[j], d1 = dbih[j+NHD], d2 = dbih[j+2*NHD];
    __shared__ float wlds[2][3][1024];
    __shared__ float hs[64*132];
    __shared__ float red[2][3][64];
    // stage M rows: 2 cols x 3 gates x 1024 = 1536 float4
    for (int q = tid; q < 1536; q += 256){
        int w = q / 768;
        int rem = q % 768;
        int p = rem / 256;
        int kk = (rem % 256)*4;
        *(float4*)&wlds[w][p][kk] = *(const float4*)&M[(size_t)(blockIdx.x*2 + w + p*NHD)*NHD + kk];
    }
    __syncthreads();
    for (int i = 0; i < NS; ++i){
        float g0, g1, g2;
        if (i == 0){ g0 = d0; g1 = d1; g2 = d2; }
        else {
            const float* hp = H + (size_t)(i-1)*NHD*NB;
            float a0 = 0.f, a1 = 0.f, a2 = 0.f;
            for (int c = 0; c < 8; ++c){
                int cb = c*128;
                __syncthreads();
                #pragma unroll
                for (int q = 0; q < 8; ++q){
                    int kloc = q*16 + ks*4;
                    float4 v;
                    v.x = hp[(size_t)(cb+kloc+0)*NB + b];
                    v.y = hp[(size_t)(cb+kloc+1)*NB + b];
                    v.z = hp[(size_t)(cb+kloc+2)*NB + b];
                    v.w = hp[(size_t)(cb+kloc+3)*NB + b];
                    *(float4*)&hs[b*132 + kloc] = v;
                }
                __syncthreads();
                if ((c >> 2) == kh){
                    const float* hrow = &hs[b*132];
                    const float* m0 = &wlds[u][0][cb];
                    const float* m1 = &wlds[u][1][cb];
                    const float* m2 = &wlds[u][2][cb];
                    #pragma unroll 4
                    for (int kq = 0; kq < 32; ++kq){
                        float4 h4 = *(const float4*)(hrow + kq*4);
                        float4 wa = *(const float4*)(m0 + kq*4);
                        float4 wb = *(const float4*)(m1 + kq*4);
                        float4 wc = *(const float4*)(m2 + kq*4);
                        a0 += h4.x*wa.x + h4.y*wa.y + h4.z*wa.z + h4.w*wa.w;
                        a1 += h4.x*wb.x + h4.y*wb.y + h4.z*wb.z + h4.w*wb.w;
                        a2 += h4.x*wc.x + h4.y*wc.y + h4.z*wc.z + h4.w*wc.w;
                    }
                }
            }
            if (kh == 1){
                red[u][0][b] = a0; red[u][1][b] = a1; red[u][2][b] = a2;
            }
            __syncthreads();
            if (kh == 0){
                a0 += red[u][0][b]; a1 += red[u][1][b]; a2 += red[u][2][b];
            }
            g0 = a0 + c0; g1 = a1 + c1; g2 = a2 + c2;
        }
        if (kh == 0){
            size_t gb = (size_t)i*NGD*NB + b;
            float ghr = __bfloat162float(Gctx[gb + (size_t)j*NB]);
            float ghz = __bfloat162float(Gctx[gb + (size_t)(j+NHD)*NB]);
            float ghn = __bfloat162float(Gctx[gb + (size_t)(j+2*NHD)*NB]);
            float cv  = __bfloat162float(ctxT[((size_t)i*NHD + j)*NB + b]);
            float r  = sigmf(g0 + ghr);
            float zg = sigmf(g1 + ghz);
            float n  = tanhf(g2 + r*ghn);
            float hn = (1.0f - zg)*n + zg*cv;
            H[((size_t)i*NHD + j)*NB + b] = hn;
        }
        gridbar(bar, i+1, 32);
    }
}

// ---------------- host launcher ----------------
extern "C" void kernel_launch(void* const* d_in, const int* in_sizes, int n_in,
                              void* d_out, int out_size, void* d_ws, size_t ws_size,
                              hipStream_t stream){
    const float* x   = (const float*)d_in[0];
    const float* eps = (const float*)d_in[1];
    const float* Wih[4]; const float* Whh[4]; const float* bih[4]; const float* bhh[4];
    for (int d = 0; d < 4; ++d){
        Wih[d] = (const float*)d_in[2 + 4*d];
        Whh[d] = (const float*)d_in[3 + 4*d];
        bih[d] = (const float*)d_in[4 + 4*d];
        bhh[d] = (const float*)d_in[5 + 4*d];
    }
    const float* dWih  = (const float*)d_in[18];
    const float* dWhh  = (const float*)d_in[19];
    const float* dbih  = (const float*)d_in[20];
    const float* dbhh  = (const float*)d_in[21];
    const float* attnW = (const float*)d_in[22];
    const float* attnb = (const float*)d_in[23];
    const float* linW  = (const float*)d_in[24];
    const float* linb  = (const float*)d_in[25];

    float* out    = (float*)d_out;
    float* outRec = out;
    float* outMu  = out + 8388608;
    float* outLv  = out + 25165824;

    char* ws = (char*)d_ws;
    bf16*  Xg    = (bf16*)(ws + 0);              // 201326592   (dead after encoder)
    bf16*  Gctx  = (bf16*)(ws + 0);              // 100663296   (reuses Xg space)
    float* Hdec  = (float*)(ws + 100663296);     // 67108864    (reuses Xg space)
    float* hh    = (float*)(ws + 201326592);     // 134217728
    bf16*  zbuf  = (bf16*)(ws + 335544320);      // 33554432
    bf16*  ctxT  = (bf16*)(ws + 369098752);      // 33554432
    float* Mbuf  = (float*)(ws + 402653184);     // 12582912
    float* sx    = (float*)(ws + 415236096);     // 65536
    float* esb   = (float*)(ws + 415301632);     // 65536
    float* Se    = (float*)(ws + 415367168);     // 4096
    float* Tbuf  = (float*)(ws + 415371264);     // 262144
    float* cvec  = (float*)(ws + 415633408);     // 12288
    unsigned int* barE = (unsigned int*)(ws + 415645696);  // 4096
    unsigned int* barD = (unsigned int*)(ws + 415649792);  // 4096

    // zero barrier state (deterministic per launch; graph-capture-safe)
    hipMemsetAsync(ws + 415645696, 0, 8192, stream);

    // phase 0: parallel prep
    hipLaunchKernelGGL(k_gemm_M, dim3(48,16), dim3(256), 0, stream, dWih, linW, Mbuf);
    hipLaunchKernelGGL(k_cvec, dim3(768), dim3(256), 0, stream, dWih, linb, dbih, cvec);
    hipLaunchKernelGGL(k_sx, dim3(4096), dim3(256), 0, stream, x, attnW, attnb, sx);
    hipLaunchKernelGGL(k_softprep2, dim3(64), dim3(256), 0, stream, sx, esb, Se);
    hipLaunchKernelGGL(k_gemm_xg, dim3(256,24,4), dim3(256), 0, stream,
                       x, Wih[0], Wih[1], Wih[2], Wih[3], bih[0], bih[1], bih[2], bih[3], Xg);

    // phase 1: encoder recurrence -> hh
    {
        void* a[] = { (void*)&Xg, (void*)&Whh[0], (void*)&Whh[1], (void*)&Whh[2], (void*)&Whh[3],
                      (void*)&bhh[0], (void*)&bhh[1], (void*)&bhh[2], (void*)&bhh[3],
                      (void*)&hh, (void*)&barE };
        hipLaunchCooperativeKernel((void*)k_encoder4, dim3(512), dim3(256), a, 0, stream);
    }

    // phase 2: z, attention statics, Gctx; mu/logvar output transpose
    hipLaunchKernelGGL(k_zexp2, dim3(4096), dim3(256), 0, stream, hh, eps, zbuf);
    hipLaunchKernelGGL(k_outT, dim3(8192), dim3(256), 0, stream, hh, outMu, outLv);
    hipLaunchKernelGGL(k_T2, dim3(1024), dim3(256), 0, stream, zbuf, esb, Tbuf);
    hipLaunchKernelGGL(k_ctx2, dim3(4096), dim3(256), 0, stream, zbuf, esb, Se, Tbuf, ctxT);
    hipLaunchKernelGGL(k_gemm_gctx, dim3(256,48), dim3(256), 0, stream, ctxT, dWhh, dbhh, Gctx);

    // phase 3: decoder recurrence
    {
        void* a[] = { (void*)&Mbuf, (void*)&cvec, (void*)&dbih, (void*)&Gctx, (void*)&ctxT,
                      (void*)&Hdec, (void*)&barD };
        hipLaunchCooperativeKernel((void*)k_decoder4, dim3(512), dim3(256), a, 0, stream);
    }

    // phase 4: output projection
    hipLaunchKernelGGL(k_gemm_rec, dim3(256,8), dim3(256), 0, stream, Hdec, linW, linb, outRec);
}

// Round 5
// 17022.458 us; speedup vs baseline: 2.5333x; 1.4155x over previous
//
#include <hip/hip_runtime.h>
#include <hip/hip_bf16.h>

typedef __hip_bfloat16 bf16;

#define NB 64
#define NS 256
#define ND 512
#define NHE 512
#define NHD 1024
#define NGE 1536
#define NGD 3072

static __device__ __forceinline__ float sigmf(float x){ return 1.0f/(1.0f+__expf(-x)); }
static __device__ __forceinline__ float blo(unsigned int u){ return __uint_as_float(u << 16); }
static __device__ __forceinline__ float bhi(unsigned int u){ return __uint_as_float(u & 0xffff0000u); }
static __device__ __forceinline__ float b2f(unsigned short u){ return __uint_as_float(((unsigned int)u) << 16); }

// ---- group-local barrier: 8 leaves -> root -> epoch flag ----
// per-group layout (uints): leaf[l] at base[l*16], root at base[128], flag at base[160]
static __device__ __forceinline__ void groupbar(unsigned int* base, int step, int perleaf, int wl){
    __syncthreads();
    if (threadIdx.x == 0){
        __threadfence();   // release
        unsigned int old = __hip_atomic_fetch_add(base + (wl & 7)*16, 1u, __ATOMIC_RELAXED, __HIP_MEMORY_SCOPE_AGENT);
        if ((old & (unsigned)(perleaf-1)) == (unsigned)(perleaf-1)){
            unsigned int r = __hip_atomic_fetch_add(base + 128, 1u, __ATOMIC_RELAXED, __HIP_MEMORY_SCOPE_AGENT);
            if ((r & 7u) == 7u)
                __hip_atomic_store(base + 160, (unsigned int)step, __ATOMIC_RELEASE, __HIP_MEMORY_SCOPE_AGENT);
        }
        while ((int)__hip_atomic_load(base + 160, __ATOMIC_RELAXED, __HIP_MEMORY_SCOPE_AGENT) < step)
            __builtin_amdgcn_s_sleep(2);
        __threadfence();   // acquire
    }
    __syncthreads();
}

// ---------------- small prep kernels ----------------
__global__ __launch_bounds__(256) void k_sx(const float* __restrict__ x,
                                            const float* __restrict__ attnW,
                                            const float* __restrict__ attnb,
                                            float* __restrict__ sx){
    int row = blockIdx.x*4 + (threadIdx.x>>6);
    int lane = threadIdx.x & 63;
    float s = 0.f;
    for (int d = lane; d < ND; d += 64) s += x[(size_t)row*ND + d]*attnW[d];
    #pragma unroll
    for (int off = 32; off; off >>= 1) s += __shfl_down(s, off, 64);
    if (lane == 0) sx[row] = s + attnb[0];
}

__global__ __launch_bounds__(256) void k_cvec(const float* __restrict__ dWih,
                                              const float* __restrict__ linb,
                                              const float* __restrict__ dbih,
                                              float* __restrict__ cvec){
    int row = blockIdx.x*4 + (threadIdx.x>>6);
    int lane = threadIdx.x & 63;
    float s = 0.f;
    for (int d = lane; d < ND; d += 64) s += dWih[(size_t)row*ND + d]*linb[d];
    #pragma unroll
    for (int off = 32; off; off >>= 1) s += __shfl_down(s, off, 64);
    if (lane == 0) cvec[row] = s + dbih[row];
}

__global__ __launch_bounds__(256) void k_softprep2(const float* __restrict__ sx,
                                                   float* __restrict__ esb,
                                                   float* __restrict__ Se){
    int b = blockIdx.x, s = threadIdx.x;
    __shared__ float red[256];
    float v = sx[b*NS + s];
    red[s] = v; __syncthreads();
    for (int off = 128; off; off >>= 1){ if (s < off) red[s] = fmaxf(red[s], red[s+off]); __syncthreads(); }
    float mx = red[0]; __syncthreads();
    float ev = __expf(v - mx);
    esb[s*NB + b] = ev;
    red[s] = ev; __syncthreads();
    for (int off = 128; off; off >>= 1){ if (s < off) red[s] += red[s+off]; __syncthreads(); }
    if (s == 0) Se[b] = red[0];
}

// convert fp32 weight matrix to bf16
__global__ __launch_bounds__(256) void k_cvtW(const float* __restrict__ W, bf16* __restrict__ o){
    size_t i = ((size_t)blockIdx.x*256 + threadIdx.x)*4;
    float4 v = *(const float4*)(W + i);
    o[i+0] = __float2bfloat16(v.x);
    o[i+1] = __float2bfloat16(v.y);
    o[i+2] = __float2bfloat16(v.z);
    o[i+3] = __float2bfloat16(v.w);
}

// z[t][h][b] = mu + eps*exp(0.5*lv); mu/lv read from hh[dir][t][j][b]
__global__ __launch_bounds__(256) void k_zexp2(const float* __restrict__ hh,
                                               const float* __restrict__ eps,
                                               bf16* __restrict__ z){
    int t  = blockIdx.x >> 4;
    int hb = blockIdx.x & 15;
    int h0 = hb*64;
    __shared__ float ls[64*69];
    int tid = threadIdx.x;
    #pragma unroll
    for (int q = 0; q < 16; ++q){
        int bb = q*4 + (tid>>6);
        int hc = tid & 63;
        ls[bb*69 + hc] = eps[((size_t)bb*NS + t)*NHD + h0 + hc];
    }
    __syncthreads();
    int b = tid & 63;
    #pragma unroll
    for (int q = 0; q < 16; ++q){
        int hq = q*4 + (tid>>6);
        int h = h0 + hq;
        int dmu = h >> 9;
        int jm  = h & 511;
        float mu = hh[(((size_t)(dmu*NS) + t)*NHE + jm)*NB + b];
        float lv = hh[(((size_t)((2+dmu)*NS) + t)*NHE + jm)*NB + b];
        float ep = ls[b*69 + hq];
        float zv = mu + ep*__expf(0.5f*lv);
        z[((size_t)t*NHD + h)*NB + b] = __float2bfloat16(zv);
    }
}

__global__ __launch_bounds__(256) void k_T2(const bf16* __restrict__ z,
                                            const float* __restrict__ esb,
                                            float* __restrict__ T){
    int h = blockIdx.x;
    int b = threadIdx.x & 63;
    int sq = threadIdx.x >> 6;
    __shared__ float red[4][64];
    float acc = 0.f;
    #pragma unroll 8
    for (int s = sq*64; s < sq*64 + 64; ++s)
        acc += esb[s*NB + b]*__bfloat162float(z[((size_t)s*NHD + h)*NB + b]);
    red[sq][b] = acc; __syncthreads();
    if (sq == 0) T[h*NB + b] = red[0][b] + red[1][b] + red[2][b] + red[3][b];
}

__global__ __launch_bounds__(256) void k_ctx2(const bf16* __restrict__ z,
                                              const float* __restrict__ esb,
                                              const float* __restrict__ Se,
                                              const float* __restrict__ T,
                                              bf16* __restrict__ ctxT){
    int i  = blockIdx.x >> 4;
    int hb = blockIdx.x & 15;
    int b  = threadIdx.x & 63;
    float ei  = esb[i*NB + b];
    float inv = 1.0f/(Se[b] - ei);
    #pragma unroll
    for (int q = 0; q < 16; ++q){
        int h = hb*64 + q*4 + (threadIdx.x>>6);
        float zv = __bfloat162float(z[((size_t)i*NHD + h)*NB + b]);
        float cv = (T[h*NB + b] - ei*zv)*inv;
        ctxT[((size_t)i*NHD + h)*NB + b] = __float2bfloat16(cv);
    }
}

__global__ __launch_bounds__(256) void k_outT(const float* __restrict__ hh,
                                              float* __restrict__ outMu,
                                              float* __restrict__ outLv){
    int bx = blockIdx.x;
    int dir = bx >> 11;
    int t  = (bx >> 3) & 255;
    int jb = bx & 7;
    int j0 = jb*64;
    __shared__ float ls[64*65];
    int tid = threadIdx.x;
    #pragma unroll
    for (int q = 0; q < 16; ++q){
        int jj = q*4 + (tid>>6);
        ls[jj*65 + (tid&63)] = hh[(((size_t)dir*NS + t)*NHE + j0 + jj)*NB + (tid&63)];
    }
    __syncthreads();
    float* outp = (dir < 2) ? outMu : outLv;
    int colbase = (dir & 1)*512;
    #pragma unroll
    for (int q = 0; q < 16; ++q){
        int bb = q*4 + (tid>>6);
        int jj = tid & 63;
        outp[((size_t)bb*NS + t)*NHD + colbase + j0 + jj] = ls[jj*65 + bb];
    }
}

// ---------------- GEMM kernels (fp32 VALU, 64x64 tiles, 4x4/thread) ----------------
__global__ __launch_bounds__(256) void k_gemm_xg(
    const float* __restrict__ x,
    const float* __restrict__ W0, const float* __restrict__ W1,
    const float* __restrict__ W2, const float* __restrict__ W3,
    const float* __restrict__ b0, const float* __restrict__ b1,
    const float* __restrict__ b2, const float* __restrict__ b3,
    bf16* __restrict__ Xg){
    int t = blockIdx.x;
    int g0 = blockIdx.y*64;
    int dir = blockIdx.z;
    const float* W   = dir==0?W0:dir==1?W1:dir==2?W2:W3;
    const float* bih = dir==0?b0:dir==1?b1:dir==2?b2:b3;
    __shared__ float As[64][36];
    __shared__ float Bs[64][36];
    int tid = threadIdx.x, tx = tid & 15, ty = tid >> 4;
    float acc[4][4] = {};
    for (int k0 = 0; k0 < ND; k0 += 32){
        #pragma unroll
        for (int m = 0; m < 8; ++m){
            int idx = m*256 + tid;
            int row = idx >> 5, kk = idx & 31;
            As[row][kk] = x[((size_t)row*NS + t)*ND + k0 + kk];
            Bs[row][kk] = W[(size_t)(g0+row)*ND + k0 + kk];
        }
        __syncthreads();
        #pragma unroll
        for (int k4 = 0; k4 < 8; ++k4){
            float4 a[4], bb[4];
            #pragma unroll
            for (int i = 0; i < 4; ++i) a[i]  = *(const float4*)&As[ty*4+i][k4*4];
            #pragma unroll
            for (int j = 0; j < 4; ++j) bb[j] = *(const float4*)&Bs[tx*4+j][k4*4];
            #pragma unroll
            for (int i = 0; i < 4; ++i)
                #pragma unroll
                for (int j = 0; j < 4; ++j)
                    acc[i][j] += a[i].x*bb[j].x + a[i].y*bb[j].y + a[i].z*bb[j].z + a[i].w*bb[j].w;
        }
        __syncthreads();
    }
    size_t base = ((size_t)(dir*NS + t)*NGE + g0)*NB;
    #pragma unroll
    for (int j = 0; j < 4; ++j){
        float bi = bih[g0 + tx*4 + j];
        #pragma unroll
        for (int i = 0; i < 4; ++i)
            Xg[base + (size_t)(tx*4+j)*NB + ty*4 + i] = __float2bfloat16(acc[i][j] + bi);
    }
}

__global__ __launch_bounds__(256) void k_gemm_gctx(
    const bf16* __restrict__ ctxT,
    const float* __restrict__ Whh,
    const float* __restrict__ bhh,
    bf16* __restrict__ Gctx){
    int i = blockIdx.x;
    int g0 = blockIdx.y*64;
    __shared__ float As[64][36];
    __shared__ float Bs[64][36];
    int tid = threadIdx.x, tx = tid & 15, ty = tid >> 4;
    float acc[4][4] = {};
    for (int k0 = 0; k0 < NHD; k0 += 32){
        #pragma unroll
        for (int m = 0; m < 8; ++m){
            int idx = m*256 + tid;
            int bb2 = idx & 63, kk = idx >> 6;
            As[bb2][kk] = __bfloat162float(ctxT[((size_t)i*NHD + k0 + kk)*NB + bb2]);
            int row = idx >> 5, k2 = idx & 31;
            Bs[row][k2] = Whh[(size_t)(g0+row)*NHD + k0 + k2];
        }
        __syncthreads();
        #pragma unroll
        for (int k4 = 0; k4 < 8; ++k4){
            float4 a[4], bb[4];
            #pragma unroll
            for (int i2 = 0; i2 < 4; ++i2) a[i2]  = *(const float4*)&As[ty*4+i2][k4*4];
            #pragma unroll
            for (int j = 0; j < 4; ++j)   bb[j] = *(const float4*)&Bs[tx*4+j][k4*4];
            #pragma unroll
            for (int i2 = 0; i2 < 4; ++i2)
                #pragma unroll
                for (int j = 0; j < 4; ++j)
                    acc[i2][j] += a[i2].x*bb[j].x + a[i2].y*bb[j].y + a[i2].z*bb[j].z + a[i2].w*bb[j].w;
        }
        __syncthreads();
    }
    size_t base = ((size_t)i*NGD + g0)*NB;
    #pragma unroll
    for (int j = 0; j < 4; ++j){
        float bi = bhh[g0 + tx*4 + j];
        #pragma unroll
        for (int i2 = 0; i2 < 4; ++i2)
            Gctx[base + (size_t)(tx*4+j)*NB + ty*4 + i2] = __float2bfloat16(acc[i2][j] + bi);
    }
}

__global__ __launch_bounds__(256) void k_gemm_rec(
    const float* __restrict__ H,
    const float* __restrict__ linW,
    const float* __restrict__ linb,
    float* __restrict__ outRec){
    int i = blockIdx.x;
    int d0 = blockIdx.y*64;
    __shared__ float As[64][36];
    __shared__ float Bs[64][36];
    int tid = threadIdx.x, tx = tid & 15, ty = tid >> 4;
    float acc[4][4] = {};
    for (int k0 = 0; k0 < NHD; k0 += 32){
        #pragma unroll
        for (int m = 0; m < 8; ++m){
            int idx = m*256 + tid;
            int bb2 = idx & 63, kk = idx >> 6;
            As[bb2][kk] = H[((size_t)i*NHD + k0 + kk)*NB + bb2];
            int row = idx >> 5, k2 = idx & 31;
            Bs[row][k2] = linW[(size_t)(d0+row)*NHD + k0 + k2];
        }
        __syncthreads();
        #pragma unroll
        for (int k4 = 0; k4 < 8; ++k4){
            float4 a[4], bb[4];
            #pragma unroll
            for (int i2 = 0; i2 < 4; ++i2) a[i2]  = *(const float4*)&As[ty*4+i2][k4*4];
            #pragma unroll
            for (int j = 0; j < 4; ++j)   bb[j] = *(const float4*)&Bs[tx*4+j][k4*4];
            #pragma unroll
            for (int i2 = 0; i2 < 4; ++i2)
                #pragma unroll
                for (int j = 0; j < 4; ++j)
                    acc[i2][j] += a[i2].x*bb[j].x + a[i2].y*bb[j].y + a[i2].z*bb[j].z + a[i2].w*bb[j].w;
        }
        __syncthreads();
    }
    #pragma unroll
    for (int j = 0; j < 4; ++j){
        float lb = linb[d0 + tx*4 + j];
        #pragma unroll
        for (int i2 = 0; i2 < 4; ++i2){
            int bb2 = ty*4 + i2;
            outRec[((size_t)bb2*NS + i)*ND + d0 + tx*4 + j] = acc[i2][j] + lb;
        }
    }
}

// M[g][h] = dec_Wih @ lin_W  -> bf16 out
__global__ __launch_bounds__(256) void k_gemm_M(
    const float* __restrict__ dWih,
    const float* __restrict__ linW,
    bf16* __restrict__ M){
    int g0 = blockIdx.x*64;
    int h0 = blockIdx.y*64;
    __shared__ float As[64][36];
    __shared__ float Bs[32][68];
    int tid = threadIdx.x, tx = tid & 15, ty = tid >> 4;
    float acc[4][4] = {};
    for (int k0 = 0; k0 < ND; k0 += 32){
        #pragma unroll
        for (int m = 0; m < 8; ++m){
            int idx = m*256 + tid;
            int row = idx >> 5, kk = idx & 31;
            As[row][kk] = dWih[(size_t)(g0+row)*ND + k0 + kk];
            int k2 = idx >> 6, hh2 = idx & 63;
            Bs[k2][hh2] = linW[(size_t)(k0+k2)*NHD + h0 + hh2];
        }
        __syncthreads();
        for (int k = 0; k < 32; ++k){
            float a[4];
            #pragma unroll
            for (int i = 0; i < 4; ++i) a[i] = As[ty*4+i][k];
            float4 b4 = *(const float4*)&Bs[k][tx*4];
            #pragma unroll
            for (int i = 0; i < 4; ++i){
                acc[i][0] += a[i]*b4.x; acc[i][1] += a[i]*b4.y;
                acc[i][2] += a[i]*b4.z; acc[i][3] += a[i]*b4.w;
            }
        }
        __syncthreads();
    }
    #pragma unroll
    for (int i = 0; i < 4; ++i)
        #pragma unroll
        for (int j = 0; j < 4; ++j)
            M[(size_t)(g0+ty*4+i)*NHD + h0 + tx*4 + j] = __float2bfloat16(acc[i][j]);
}

// ---------------- recurrence kernels: batch-grouped, group-local barriers ----------------
// encoder: 256 WGs x 512thr; 16 groups = dir(4) x b-quarter(4); WG owns 32 j (96 rows bf16 in LDS)
__global__ __launch_bounds__(512, 2) void k_enc5(
    const bf16* __restrict__ Xg,
    const bf16* __restrict__ WB,     // [4][1536][512] bf16
    const float* __restrict__ b0, const float* __restrict__ b1,
    const float* __restrict__ b2, const float* __restrict__ b3,
    float* __restrict__ hh,          // [4][256][512][64] fp32 (history == exchange)
    unsigned int* __restrict__ bar){
    int wg = blockIdx.x;
    int grp = wg >> 4;
    int wl  = wg & 15;
    int dir = grp >> 2;
    int boff = (grp & 3)*16;
    int jbase = wl*32;
    int tid = threadIdx.x;
    const float* bhh = dir==0?b0:dir==1?b1:dir==2?b2:b3;
    __shared__ unsigned int Mlds[96*272];   // [96 rows][4 kq][68 uints]
    __shared__ float hs[16*548];            // [16 b][4 kq][136+ dw]
    // stage weights once: rows r = jl*3+g <- WB[dir][jbase+jl + g*512]
    {
        const uint4* Wu4 = (const uint4*)WB;
        #pragma unroll
        for (int s = 0; s < 12; ++s){
            int idx = s*512 + tid;
            int row = idx >> 6, rem = idx & 63;
            int grow = (jbase + row/3) + (row%3)*512;
            uint4 v = Wu4[((size_t)(dir*NGE + grow))*64 + rem];
            int kq = rem >> 4, kl = (rem & 15)*4;
            *(uint4*)&Mlds[row*272 + kq*68 + kl] = v;
        }
    }
    __syncthreads();
    int jl = tid >> 4;
    int bq = (tid >> 2) & 3;
    int kq = tid & 3;
    int j  = jbase + jl;
    int bg = boff + bq*4;
    int r0 = jl*3;
    bool gate = (kq == 0);
    float br=0, bz=0, bn=0;
    if (gate){ br = bhh[j]; bz = bhh[j+512]; bn = bhh[j+1024]; }
    float hprev[4] = {0.f,0.f,0.f,0.f};
    unsigned int* gb = bar + grp*256;
    for (int t = 0; t < NS; ++t){
        int tcur = (dir & 1) ? (255 - t) : t;
        float a[3][4] = {};
        if (t > 0){
            int tprev = (dir & 1) ? (256 - t) : (t - 1);
            const float* hp = hh + (size_t)(dir*NS + tprev)*NHE*NB;
            #pragma unroll
            for (int s = 0; s < 4; ++s){
                int f = s*512 + tid;
                int k = f >> 2, bq4 = f & 3;
                float4 v = *(const float4*)(hp + (size_t)k*NB + boff + bq4*4);
                int base = (bq4*4)*548 + (k>>7)*136 + (k&127);
                hs[base] = v.x; hs[base+548] = v.y; hs[base+1096] = v.z; hs[base+1644] = v.w;
            }
            __syncthreads();
            #pragma unroll 2
            for (int ko = 0; ko < 16; ++ko){
                float4 h4a[4], h4b[4];
                #pragma unroll
                for (int bi = 0; bi < 4; ++bi){
                    int ha = (bq*4+bi)*548 + kq*136 + ko*8;
                    h4a[bi] = *(const float4*)&hs[ha];
                    h4b[bi] = *(const float4*)&hs[ha + 4];
                }
                #pragma unroll
                for (int g = 0; g < 3; ++g){
                    uint4 mu = *(const uint4*)&Mlds[(r0+g)*272 + kq*68 + ko*4];
                    float m0 = blo(mu.x), m1 = bhi(mu.x), m2 = blo(mu.y), m3 = bhi(mu.y);
                    float m4 = blo(mu.z), m5 = bhi(mu.z), m6 = blo(mu.w), m7 = bhi(mu.w);
                    #pragma unroll
                    for (int bi = 0; bi < 4; ++bi){
                        a[g][bi] += h4a[bi].x*m0 + h4a[bi].y*m1 + h4a[bi].z*m2 + h4a[bi].w*m3
                                  + h4b[bi].x*m4 + h4b[bi].y*m5 + h4b[bi].z*m6 + h4b[bi].w*m7;
                    }
                }
            }
        }
        #pragma unroll
        for (int g = 0; g < 3; ++g)
            #pragma unroll
            for (int bi = 0; bi < 4; ++bi){
                float v = a[g][bi];
                v += __shfl_xor(v, 1, 64);
                v += __shfl_xor(v, 2, 64);
                a[g][bi] = v;
            }
        if (gate){
            size_t xrow = (size_t)(dir*NS + tcur)*NGE;
            ushort4 xr = *(const ushort4*)(Xg + (xrow + j)*NB + bg);
            ushort4 xz = *(const ushort4*)(Xg + (xrow + j + 512)*NB + bg);
            ushort4 xn = *(const ushort4*)(Xg + (xrow + j + 1024)*NB + bg);
            float4 ho;
            {
                float r0g = sigmf(b2f(xr.x) + a[0][0] + br);
                float zg  = sigmf(b2f(xz.x) + a[1][0] + bz);
                float n   = tanhf(b2f(xn.x) + r0g*(a[2][0] + bn));
                hprev[0] = (1.0f - zg)*n + zg*hprev[0]; ho.x = hprev[0];
            }
            {
                float r0g = sigmf(b2f(xr.y) + a[0][1] + br);
                float zg  = sigmf(b2f(xz.y) + a[1][1] + bz);
                float n   = tanhf(b2f(xn.y) + r0g*(a[2][1] + bn));
                hprev[1] = (1.0f - zg)*n + zg*hprev[1]; ho.y = hprev[1];
            }
            {
                float r0g = sigmf(b2f(xr.z) + a[0][2] + br);
                float zg  = sigmf(b2f(xz.z) + a[1][2] + bz);
                float n   = tanhf(b2f(xn.z) + r0g*(a[2][2] + bn));
                hprev[2] = (1.0f - zg)*n + zg*hprev[2]; ho.z = hprev[2];
            }
            {
                float r0g = sigmf(b2f(xr.w) + a[0][3] + br);
                float zg  = sigmf(b2f(xz.w) + a[1][3] + bz);
                float n   = tanhf(b2f(xn.w) + r0g*(a[2][3] + bn));
                hprev[3] = (1.0f - zg)*n + zg*hprev[3]; ho.w = hprev[3];
            }
            *(float4*)(hh + ((size_t)(dir*NS + tcur)*NHE + j)*NB + bg) = ho;
        }
        groupbar(gb, t+1, 2, wl);
    }
}

// decoder: 256 WGs x 512thr; 4 groups x 64 WGs (b-width 16); WG owns 16 j (48 rows bf16 in LDS)
__global__ __launch_bounds__(512, 2) void k_dec5(
    const bf16* __restrict__ MB,     // [3072][1024] bf16
    const float* __restrict__ cvec,
    const float* __restrict__ dbih,
    const bf16* __restrict__ Gctx,
    const bf16* __restrict__ ctxT,
    float* __restrict__ H,           // [256][1024][64] fp32
    bf16* __restrict__ Ht,           // [256][64][1024] bf16 (exchange)
    unsigned int* __restrict__ bar){
    int wg = blockIdx.x;
    int grp = wg >> 6;
    int wl  = wg & 63;
    int boff = grp*16;
    int jbase = wl*16;
    int tid = threadIdx.x;
    __shared__ unsigned int Mlds[48*560];   // [48 rows][8 kq][68 uints]
    __shared__ unsigned int hsu[16*548];    // [16 b][8 kq][68 uints] (bf16 pairs)
    {
        const uint4* Mu4 = (const uint4*)MB;
        #pragma unroll
        for (int s = 0; s < 12; ++s){
            int idx = s*512 + tid;
            int row = idx >> 7, rem = idx & 127;
            int grow = (jbase + row/3) + (row%3)*NHD;
            uint4 v = Mu4[(size_t)grow*128 + rem];
            int kq = rem >> 4, kl = (rem & 15)*4;
            *(uint4*)&Mlds[row*560 + kq*68 + kl] = v;
        }
    }
    __syncthreads();
    int jl = tid >> 5;
    int bq = (tid >> 3) & 3;
    int kq = tid & 7;
    int j  = jbase + jl;
    int bg = boff + bq*4;
    int r0 = jl*3;
    bool gate = (kq == 0);
    float c0=0,c1=0,c2=0,d0v=0,d1v=0,d2v=0;
    if (gate){
        c0 = cvec[j]; c1 = cvec[j+NHD]; c2 = cvec[j+2*NHD];
        d0v = dbih[j]; d1v = dbih[j+NHD]; d2v = dbih[j+2*NHD];
    }
    unsigned int* gb = bar + grp*256;
    for (int i = 0; i < NS; ++i){
        float a[3][4] = {};
        if (i > 0){
            const uint4* hp = (const uint4*)Ht + ((size_t)(i-1)*NB)*128;
            #pragma unroll
            for (int s = 0; s < 4; ++s){
                int f = s*512 + tid;
                int brow = f >> 7, ko8 = f & 127;
                uint4 v = hp[(size_t)(boff + brow)*128 + ko8];
                int kq2 = ko8 >> 4, kl = (ko8 & 15)*4;
                *(uint4*)&hsu[brow*548 + kq2*68 + kl] = v;
            }
            __syncthreads();
            #pragma unroll 2
            for (int ko = 0; ko < 16; ++ko){
                float hf[4][8];
                #pragma unroll
                for (int bi = 0; bi < 4; ++bi){
                    uint4 hv = *(const uint4*)&hsu[(bq*4+bi)*548 + kq*68 + ko*4];
                    hf[bi][0] = blo(hv.x); hf[bi][1] = bhi(hv.x);
                    hf[bi][2] = blo(hv.y); hf[bi][3] = bhi(hv.y);
                    hf[bi][4] = blo(hv.z); hf[bi][5] = bhi(hv.z);
                    hf[bi][6] = blo(hv.w); hf[bi][7] = bhi(hv.w);
                }
                #pragma unroll
                for (int g = 0; g < 3; ++g){
                    uint4 mu = *(const uint4*)&Mlds[(r0+g)*560 + kq*68 + ko*4];
                    float m0 = blo(mu.x), m1 = bhi(mu.x), m2 = blo(mu.y), m3 = bhi(mu.y);
                    float m4 = blo(mu.z), m5 = bhi(mu.z), m6 = blo(mu.w), m7 = bhi(mu.w);
                    #pragma unroll
                    for (int bi = 0; bi < 4; ++bi){
                        a[g][bi] += hf[bi][0]*m0 + hf[bi][1]*m1 + hf[bi][2]*m2 + hf[bi][3]*m3
                                  + hf[bi][4]*m4 + hf[bi][5]*m5 + hf[bi][6]*m6 + hf[bi][7]*m7;
                    }
                }
            }
        }
        #pragma unroll
        for (int g = 0; g < 3; ++g)
            #pragma unroll
            for (int bi = 0; bi < 4; ++bi){
                float v = a[g][bi];
                v += __shfl_xor(v, 1, 64);
                v += __shfl_xor(v, 2, 64);
                v += __shfl_xor(v, 4, 64);
                a[g][bi] = v;
            }
        if (gate){
            size_t gbx = (size_t)i*NGD*NB;
            ushort4 gr = *(const ushort4*)(Gctx + gbx + (size_t)j*NB + bg);
            ushort4 gz = *(const ushort4*)(Gctx + gbx + (size_t)(j+NHD)*NB + bg);
            ushort4 gn = *(const ushort4*)(Gctx + gbx + (size_t)(j+2*NHD)*NB + bg);
            ushort4 cx = *(const ushort4*)(ctxT + ((size_t)i*NHD + j)*NB + bg);
            float4 ho;
            float g0v, g1v, g2v, rg, zg, nn;
            unsigned short hb[4];
            g0v = (i==0)? d0v : a[0][0] + c0;
            g1v = (i==0)? d1v : a[1][0] + c1;
            g2v = (i==0)? d2v : a[2][0] + c2;
            rg = sigmf(g0v + b2f(gr.x)); zg = sigmf(g1v + b2f(gz.x));
            nn = tanhf(g2v + rg*b2f(gn.x));
            ho.x = (1.0f - zg)*nn + zg*b2f(cx.x);
            g0v = (i==0)? d0v : a[0][1] + c0;
            g1v = (i==0)? d1v : a[1][1] + c1;
            g2v = (i==0)? d2v : a[2][1] + c2;
            rg = sigmf(g0v + b2f(gr.y)); zg = sigmf(g1v + b2f(gz.y));
            nn = tanhf(g2v + rg*b2f(gn.y));
            ho.y = (1.0f - zg)*nn + zg*b2f(cx.y);
            g0v = (i==0)? d0v : a[0][2] + c0;
            g1v = (i==0)? d1v : a[1][2] + c1;
            g2v = (i==0)? d2v : a[2][2] + c2;
            rg = sigmf(g0v + b2f(gr.z)); zg = sigmf(g1v + b2f(gz.z));
            nn = tanhf(g2v + rg*b2f(gn.z));
            ho.z = (1.0f - zg)*nn + zg*b2f(cx.z);
            g0v = (i==0)? d0v : a[0][3] + c0;
            g1v = (i==0)? d1v : a[1][3] + c1;
            g2v = (i==0)? d2v : a[2][3] + c2;
            rg = sigmf(g0v + b2f(gr.w)); zg = sigmf(g1v + b2f(gz.w));
            nn = tanhf(g2v + rg*b2f(gn.w));
            ho.w = (1.0f - zg)*nn + zg*b2f(cx.w);
            *(float4*)(H + ((size_t)i*NHD + j)*NB + bg) = ho;
            Ht[((size_t)i*NB + bg + 0)*NHD + j] = __float2bfloat16(ho.x);
            Ht[((size_t)i*NB + bg + 1)*NHD + j] = __float2bfloat16(ho.y);
            Ht[((size_t)i*NB + bg + 2)*NHD + j] = __float2bfloat16(ho.z);
            Ht[((size_t)i*NB + bg + 3)*NHD + j] = __float2bfloat16(ho.w);
        }
        groupbar(gb, i+1, 8, wl);
    }
}

// ---------------- host launcher ----------------
extern "C" void kernel_launch(void* const* d_in, const int* in_sizes, int n_in,
                              void* d_out, int out_size, void* d_ws, size_t ws_size,
                              hipStream_t stream){
    const float* x   = (const float*)d_in[0];
    const float* eps = (const float*)d_in[1];
    const float* Wih[4]; const float* Whh[4]; const float* bih[4]; const float* bhh[4];
    for (int d = 0; d < 4; ++d){
        Wih[d] = (const float*)d_in[2 + 4*d];
        Whh[d] = (const float*)d_in[3 + 4*d];
        bih[d] = (const float*)d_in[4 + 4*d];
        bhh[d] = (const float*)d_in[5 + 4*d];
    }
    const float* dWih  = (const float*)d_in[18];
    const float* dWhh  = (const float*)d_in[19];
    const float* dbih  = (const float*)d_in[20];
    const float* dbhh  = (const float*)d_in[21];
    const float* attnW = (const float*)d_in[22];
    const float* attnb = (const float*)d_in[23];
    const float* linW  = (const float*)d_in[24];
    const float* linb  = (const float*)d_in[25];

    float* out    = (float*)d_out;
    float* outRec = out;
    float* outMu  = out + 8388608;
    float* outLv  = out + 25165824;

    char* ws = (char*)d_ws;
    bf16*  Xg    = (bf16*)(ws + 0);              // 201326592 (dead after encoder)
    bf16*  Gctx  = (bf16*)(ws + 0);              // 100663296 (reuses Xg)
    float* Hdec  = (float*)(ws + 100663296);     // 67108864  (reuses Xg)
    float* hh    = (float*)(ws + 201326592);     // 134217728
    bf16*  zbuf  = (bf16*)(ws + 335544320);      // 33554432
    bf16*  ctxT  = (bf16*)(ws + 369098752);      // 33554432
    bf16*  MbufB = (bf16*)(ws + 402653184);      // 6291456
    bf16*  WhhB  = (bf16*)(ws + 408944640);      // 6291456
    bf16*  Ht    = (bf16*)(ws + 415236096);      // 33554432
    float* sx    = (float*)(ws + 448790528);     // 65536
    float* esb   = (float*)(ws + 448856064);     // 65536
    float* Se    = (float*)(ws + 448921600);     // 4096
    float* Tbuf  = (float*)(ws + 448925696);     // 262144
    float* cvec  = (float*)(ws + 449187840);     // 12288
    unsigned int* barE = (unsigned int*)(ws + 449200128);  // 16384
    unsigned int* barD = (unsigned int*)(ws + 449216512);  // 16384

    hipMemsetAsync(ws + 449200128, 0, 32768, stream);

    // phase 0: parallel prep
    hipLaunchKernelGGL(k_gemm_M, dim3(48,16), dim3(256), 0, stream, dWih, linW, MbufB);
    for (int d = 0; d < 4; ++d)
        hipLaunchKernelGGL(k_cvtW, dim3(768), dim3(256), 0, stream, Whh[d], WhhB + (size_t)d*NGE*NHE);
    hipLaunchKernelGGL(k_cvec, dim3(768), dim3(256), 0, stream, dWih, linb, dbih, cvec);
    hipLaunchKernelGGL(k_sx, dim3(4096), dim3(256), 0, stream, x, attnW, attnb, sx);
    hipLaunchKernelGGL(k_softprep2, dim3(64), dim3(256), 0, stream, sx, esb, Se);
    hipLaunchKernelGGL(k_gemm_xg, dim3(256,24,4), dim3(256), 0, stream,
                       x, Wih[0], Wih[1], Wih[2], Wih[3], bih[0], bih[1], bih[2], bih[3], Xg);

    // phase 1: encoder recurrence -> hh
    {
        void* a[] = { (void*)&Xg, (void*)&WhhB,
                      (void*)&bhh[0], (void*)&bhh[1], (void*)&bhh[2], (void*)&bhh[3],
                      (void*)&hh, (void*)&barE };
        hipLaunchCooperativeKernel((void*)k_enc5, dim3(256), dim3(512), a, 0, stream);
    }

    // phase 2: z, attention statics, Gctx; mu/logvar output transpose
    hipLaunchKernelGGL(k_zexp2, dim3(4096), dim3(256), 0, stream, hh, eps, zbuf);
    hipLaunchKernelGGL(k_outT, dim3(8192), dim3(256), 0, stream, hh, outMu, outLv);
    hipLaunchKernelGGL(k_T2, dim3(1024), dim3(256), 0, stream, zbuf, esb, Tbuf);
    hipLaunchKernelGGL(k_ctx2, dim3(4096), dim3(256), 0, stream, zbuf, esb, Se, Tbuf, ctxT);
    hipLaunchKernelGGL(k_gemm_gctx, dim3(256,48), dim3(256), 0, stream, ctxT, dWhh, dbhh, Gctx);

    // phase 3: decoder recurrence
    {
        void* a[] = { (void*)&MbufB, (void*)&cvec, (void*)&dbih, (void*)&Gctx, (void*)&ctxT,
                      (void*)&Hdec, (void*)&Ht, (void*)&barD };
        hipLaunchCooperativeKernel((void*)k_dec5, dim3(256), dim3(512), a, 0, stream);
    }

    // phase 4: output projection
    hipLaunchKernelGGL(k_gemm_rec, dim3(256,8), dim3(256), 0, stream, Hdec, linW, linb, outRec);
}

// Round 6
// 13081.195 us; speedup vs baseline: 3.2966x; 1.3013x over previous
//
#include <hip/hip_runtime.h>
#include <hip/hip_bf16.h>

typedef __hip_bfloat16 bf16;
typedef __attribute__((ext_vector_type(8))) short s8v;
typedef __attribute__((ext_vector_type(4))) float f32x4;

#define NB 64
#define NS 256
#define ND 512
#define NHE 512
#define NHD 1024
#define NGE 1536
#define NGD 3072

static __device__ __forceinline__ float sigmf(float x){ return 1.0f/(1.0f+__expf(-x)); }
static __device__ __forceinline__ float b2f(unsigned short u){ return __uint_as_float(((unsigned int)u) << 16); }

// ---- group-local barrier: 8 leaves -> root -> epoch flag ----
static __device__ __forceinline__ void groupbar(unsigned int* base, int step, int perleaf, int wl){
    __syncthreads();
    if (threadIdx.x == 0){
        __threadfence();   // release
        unsigned int old = __hip_atomic_fetch_add(base + (wl & 7)*16, 1u, __ATOMIC_RELAXED, __HIP_MEMORY_SCOPE_AGENT);
        if ((old & (unsigned)(perleaf-1)) == (unsigned)(perleaf-1)){
            unsigned int r = __hip_atomic_fetch_add(base + 128, 1u, __ATOMIC_RELAXED, __HIP_MEMORY_SCOPE_AGENT);
            if ((r & 7u) == 7u)
                __hip_atomic_store(base + 160, (unsigned int)step, __ATOMIC_RELEASE, __HIP_MEMORY_SCOPE_AGENT);
        }
        while ((int)__hip_atomic_load(base + 160, __ATOMIC_RELAXED, __HIP_MEMORY_SCOPE_AGENT) < step)
            __builtin_amdgcn_s_sleep(2);
        __threadfence();   // acquire
    }
    __syncthreads();
}

// ---------------- small prep kernels ----------------
__global__ __launch_bounds__(256) void k_sx(const float* __restrict__ x,
                                            const float* __restrict__ attnW,
                                            const float* __restrict__ attnb,
                                            float* __restrict__ sx){
    int row = blockIdx.x*4 + (threadIdx.x>>6);
    int lane = threadIdx.x & 63;
    float s = 0.f;
    for (int d = lane; d < ND; d += 64) s += x[(size_t)row*ND + d]*attnW[d];
    #pragma unroll
    for (int off = 32; off; off >>= 1) s += __shfl_down(s, off, 64);
    if (lane == 0) sx[row] = s + attnb[0];
}

__global__ __launch_bounds__(256) void k_cvec(const float* __restrict__ dWih,
                                              const float* __restrict__ linb,
                                              const float* __restrict__ dbih,
                                              float* __restrict__ cvec){
    int row = blockIdx.x*4 + (threadIdx.x>>6);
    int lane = threadIdx.x & 63;
    float s = 0.f;
    for (int d = lane; d < ND; d += 64) s += dWih[(size_t)row*ND + d]*linb[d];
    #pragma unroll
    for (int off = 32; off; off >>= 1) s += __shfl_down(s, off, 64);
    if (lane == 0) cvec[row] = s + dbih[row];
}

__global__ __launch_bounds__(256) void k_softprep2(const float* __restrict__ sx,
                                                   float* __restrict__ esb,
                                                   float* __restrict__ Se){
    int b = blockIdx.x, s = threadIdx.x;
    __shared__ float red[256];
    float v = sx[b*NS + s];
    red[s] = v; __syncthreads();
    for (int off = 128; off; off >>= 1){ if (s < off) red[s] = fmaxf(red[s], red[s+off]); __syncthreads(); }
    float mx = red[0]; __syncthreads();
    float ev = __expf(v - mx);
    esb[s*NB + b] = ev;
    red[s] = ev; __syncthreads();
    for (int off = 128; off; off >>= 1){ if (s < off) red[s] += red[s+off]; __syncthreads(); }
    if (s == 0) Se[b] = red[0];
}

__global__ __launch_bounds__(256) void k_cvtW(const float* __restrict__ W, bf16* __restrict__ o){
    size_t i = ((size_t)blockIdx.x*256 + threadIdx.x)*4;
    float4 v = *(const float4*)(W + i);
    o[i+0] = __float2bfloat16(v.x);
    o[i+1] = __float2bfloat16(v.y);
    o[i+2] = __float2bfloat16(v.z);
    o[i+3] = __float2bfloat16(v.w);
}

__global__ __launch_bounds__(256) void k_zexp2(const float* __restrict__ hh,
                                               const float* __restrict__ eps,
                                               bf16* __restrict__ z){
    int t  = blockIdx.x >> 4;
    int hb = blockIdx.x & 15;
    int h0 = hb*64;
    __shared__ float ls[64*69];
    int tid = threadIdx.x;
    #pragma unroll
    for (int q = 0; q < 16; ++q){
        int bb = q*4 + (tid>>6);
        int hc = tid & 63;
        ls[bb*69 + hc] = eps[((size_t)bb*NS + t)*NHD + h0 + hc];
    }
    __syncthreads();
    int b = tid & 63;
    #pragma unroll
    for (int q = 0; q < 16; ++q){
        int hq = q*4 + (tid>>6);
        int h = h0 + hq;
        int dmu = h >> 9;
        int jm  = h & 511;
        float mu = hh[(((size_t)(dmu*NS) + t)*NHE + jm)*NB + b];
        float lv = hh[(((size_t)((2+dmu)*NS) + t)*NHE + jm)*NB + b];
        float ep = ls[b*69 + hq];
        float zv = mu + ep*__expf(0.5f*lv);
        z[((size_t)t*NHD + h)*NB + b] = __float2bfloat16(zv);
    }
}

__global__ __launch_bounds__(256) void k_T2(const bf16* __restrict__ z,
                                            const float* __restrict__ esb,
                                            float* __restrict__ T){
    int h = blockIdx.x;
    int b = threadIdx.x & 63;
    int sq = threadIdx.x >> 6;
    __shared__ float red[4][64];
    float acc = 0.f;
    #pragma unroll 8
    for (int s = sq*64; s < sq*64 + 64; ++s)
        acc += esb[s*NB + b]*__bfloat162float(z[((size_t)s*NHD + h)*NB + b]);
    red[sq][b] = acc; __syncthreads();
    if (sq == 0) T[h*NB + b] = red[0][b] + red[1][b] + red[2][b] + red[3][b];
}

__global__ __launch_bounds__(256) void k_ctx2(const bf16* __restrict__ z,
                                              const float* __restrict__ esb,
                                              const float* __restrict__ Se,
                                              const float* __restrict__ T,
                                              bf16* __restrict__ ctxT){
    int i  = blockIdx.x >> 4;
    int hb = blockIdx.x & 15;
    int b  = threadIdx.x & 63;
    float ei  = esb[i*NB + b];
    float inv = 1.0f/(Se[b] - ei);
    #pragma unroll
    for (int q = 0; q < 16; ++q){
        int h = hb*64 + q*4 + (threadIdx.x>>6);
        float zv = __bfloat162float(z[((size_t)i*NHD + h)*NB + b]);
        float cv = (T[h*NB + b] - ei*zv)*inv;
        ctxT[((size_t)i*NHD + h)*NB + b] = __float2bfloat16(cv);
    }
}

__global__ __launch_bounds__(256) void k_outT(const float* __restrict__ hh,
                                              float* __restrict__ outMu,
                                              float* __restrict__ outLv){
    int bx = blockIdx.x;
    int dir = bx >> 11;
    int t  = (bx >> 3) & 255;
    int jb = bx & 7;
    int j0 = jb*64;
    __shared__ float ls[64*65];
    int tid = threadIdx.x;
    #pragma unroll
    for (int q = 0; q < 16; ++q){
        int jj = q*4 + (tid>>6);
        ls[jj*65 + (tid&63)] = hh[(((size_t)dir*NS + t)*NHE + j0 + jj)*NB + (tid&63)];
    }
    __syncthreads();
    float* outp = (dir < 2) ? outMu : outLv;
    int colbase = (dir & 1)*512;
    #pragma unroll
    for (int q = 0; q < 16; ++q){
        int bb = q*4 + (tid>>6);
        int jj = tid & 63;
        outp[((size_t)bb*NS + t)*NHD + colbase + j0 + jj] = ls[jj*65 + bb];
    }
}

// ---------------- GEMM kernels (fp32 VALU, 64x64 tiles, 4x4/thread) ----------------
__global__ __launch_bounds__(256) void k_gemm_xg(
    const float* __restrict__ x,
    const float* __restrict__ W0, const float* __restrict__ W1,
    const float* __restrict__ W2, const float* __restrict__ W3,
    const float* __restrict__ b0, const float* __restrict__ b1,
    const float* __restrict__ b2, const float* __restrict__ b3,
    bf16* __restrict__ Xg){
    int t = blockIdx.x;
    int g0 = blockIdx.y*64;
    int dir = blockIdx.z;
    const float* W   = dir==0?W0:dir==1?W1:dir==2?W2:W3;
    const float* bih = dir==0?b0:dir==1?b1:dir==2?b2:b3;
    __shared__ float As[64][36];
    __shared__ float Bs[64][36];
    int tid = threadIdx.x, tx = tid & 15, ty = tid >> 4;
    float acc[4][4] = {};
    for (int k0 = 0; k0 < ND; k0 += 32){
        #pragma unroll
        for (int m = 0; m < 8; ++m){
            int idx = m*256 + tid;
            int row = idx >> 5, kk = idx & 31;
            As[row][kk] = x[((size_t)row*NS + t)*ND + k0 + kk];
            Bs[row][kk] = W[(size_t)(g0+row)*ND + k0 + kk];
        }
        __syncthreads();
        #pragma unroll
        for (int k4 = 0; k4 < 8; ++k4){
            float4 a[4], bb[4];
            #pragma unroll
            for (int i = 0; i < 4; ++i) a[i]  = *(const float4*)&As[ty*4+i][k4*4];
            #pragma unroll
            for (int j = 0; j < 4; ++j) bb[j] = *(const float4*)&Bs[tx*4+j][k4*4];
            #pragma unroll
            for (int i = 0; i < 4; ++i)
                #pragma unroll
                for (int j = 0; j < 4; ++j)
                    acc[i][j] += a[i].x*bb[j].x + a[i].y*bb[j].y + a[i].z*bb[j].z + a[i].w*bb[j].w;
        }
        __syncthreads();
    }
    size_t base = ((size_t)(dir*NS + t)*NGE + g0)*NB;
    #pragma unroll
    for (int j = 0; j < 4; ++j){
        float bi = bih[g0 + tx*4 + j];
        #pragma unroll
        for (int i = 0; i < 4; ++i)
            Xg[base + (size_t)(tx*4+j)*NB + ty*4 + i] = __float2bfloat16(acc[i][j] + bi);
    }
}

__global__ __launch_bounds__(256) void k_gemm_gctx(
    const bf16* __restrict__ ctxT,
    const float* __restrict__ Whh,
    const float* __restrict__ bhh,
    bf16* __restrict__ Gctx){
    int i = blockIdx.x;
    int g0 = blockIdx.y*64;
    __shared__ float As[64][36];
    __shared__ float Bs[64][36];
    int tid = threadIdx.x, tx = tid & 15, ty = tid >> 4;
    float acc[4][4] = {};
    for (int k0 = 0; k0 < NHD; k0 += 32){
        #pragma unroll
        for (int m = 0; m < 8; ++m){
            int idx = m*256 + tid;
            int bb2 = idx & 63, kk = idx >> 6;
            As[bb2][kk] = __bfloat162float(ctxT[((size_t)i*NHD + k0 + kk)*NB + bb2]);
            int row = idx >> 5, k2 = idx & 31;
            Bs[row][k2] = Whh[(size_t)(g0+row)*NHD + k0 + k2];
        }
        __syncthreads();
        #pragma unroll
        for (int k4 = 0; k4 < 8; ++k4){
            float4 a[4], bb[4];
            #pragma unroll
            for (int i2 = 0; i2 < 4; ++i2) a[i2]  = *(const float4*)&As[ty*4+i2][k4*4];
            #pragma unroll
            for (int j = 0; j < 4; ++j)   bb[j] = *(const float4*)&Bs[tx*4+j][k4*4];
            #pragma unroll
            for (int i2 = 0; i2 < 4; ++i2)
                #pragma unroll
                for (int j = 0; j < 4; ++j)
                    acc[i2][j] += a[i2].x*bb[j].x + a[i2].y*bb[j].y + a[i2].z*bb[j].z + a[i2].w*bb[j].w;
        }
        __syncthreads();
    }
    size_t base = ((size_t)i*NGD + g0)*NB;
    #pragma unroll
    for (int j = 0; j < 4; ++j){
        float bi = bhh[g0 + tx*4 + j];
        #pragma unroll
        for (int i2 = 0; i2 < 4; ++i2)
            Gctx[base + (size_t)(tx*4+j)*NB + ty*4 + i2] = __float2bfloat16(acc[i2][j] + bi);
    }
}

__global__ __launch_bounds__(256) void k_gemm_rec(
    const float* __restrict__ H,
    const float* __restrict__ linW,
    const float* __restrict__ linb,
    float* __restrict__ outRec){
    int i = blockIdx.x;
    int d0 = blockIdx.y*64;
    __shared__ float As[64][36];
    __shared__ float Bs[64][36];
    int tid = threadIdx.x, tx = tid & 15, ty = tid >> 4;
    float acc[4][4] = {};
    for (int k0 = 0; k0 < NHD; k0 += 32){
        #pragma unroll
        for (int m = 0; m < 8; ++m){
            int idx = m*256 + tid;
            int bb2 = idx & 63, kk = idx >> 6;
            As[bb2][kk] = H[((size_t)i*NHD + k0 + kk)*NB + bb2];
            int row = idx >> 5, k2 = idx & 31;
            Bs[row][k2] = linW[(size_t)(d0+row)*NHD + k0 + k2];
        }
        __syncthreads();
        #pragma unroll
        for (int k4 = 0; k4 < 8; ++k4){
            float4 a[4], bb[4];
            #pragma unroll
            for (int i2 = 0; i2 < 4; ++i2) a[i2]  = *(const float4*)&As[ty*4+i2][k4*4];
            #pragma unroll
            for (int j = 0; j < 4; ++j)   bb[j] = *(const float4*)&Bs[tx*4+j][k4*4];
            #pragma unroll
            for (int i2 = 0; i2 < 4; ++i2)
                #pragma unroll
                for (int j = 0; j < 4; ++j)
                    acc[i2][j] += a[i2].x*bb[j].x + a[i2].y*bb[j].y + a[i2].z*bb[j].z + a[i2].w*bb[j].w;
        }
        __syncthreads();
    }
    #pragma unroll
    for (int j = 0; j < 4; ++j){
        float lb = linb[d0 + tx*4 + j];
        #pragma unroll
        for (int i2 = 0; i2 < 4; ++i2){
            int bb2 = ty*4 + i2;
            outRec[((size_t)bb2*NS + i)*ND + d0 + tx*4 + j] = acc[i2][j] + lb;
        }
    }
}

__global__ __launch_bounds__(256) void k_gemm_M(
    const float* __restrict__ dWih,
    const float* __restrict__ linW,
    bf16* __restrict__ M){
    int g0 = blockIdx.x*64;
    int h0 = blockIdx.y*64;
    __shared__ float As[64][36];
    __shared__ float Bs[32][68];
    int tid = threadIdx.x, tx = tid & 15, ty = tid >> 4;
    float acc[4][4] = {};
    for (int k0 = 0; k0 < ND; k0 += 32){
        #pragma unroll
        for (int m = 0; m < 8; ++m){
            int idx = m*256 + tid;
            int row = idx >> 5, kk = idx & 31;
            As[row][kk] = dWih[(size_t)(g0+row)*ND + k0 + kk];
            int k2 = idx >> 6, hh2 = idx & 63;
            Bs[k2][hh2] = linW[(size_t)(k0+k2)*NHD + h0 + hh2];
        }
        __syncthreads();
        for (int k = 0; k < 32; ++k){
            float a[4];
            #pragma unroll
            for (int i = 0; i < 4; ++i) a[i] = As[ty*4+i][k];
            float4 b4 = *(const float4*)&Bs[k][tx*4];
            #pragma unroll
            for (int i = 0; i < 4; ++i){
                acc[i][0] += a[i]*b4.x; acc[i][1] += a[i]*b4.y;
                acc[i][2] += a[i]*b4.z; acc[i][3] += a[i]*b4.w;
            }
        }
        __syncthreads();
    }
    #pragma unroll
    for (int i = 0; i < 4; ++i)
        #pragma unroll
        for (int j = 0; j < 4; ++j)
            M[(size_t)(g0+ty*4+i)*NHD + h0 + tx*4 + j] = __float2bfloat16(acc[i][j]);
}

// ---------------- MFMA recurrence kernels ----------------
// encoder: 256 WGs x 256 thr (4 waves). group = (dir,bq) = wg&15 (XCD-local), wl = wg>>4.
// wave (jl = wid&1, kh = wid>>1): C-tile (jt = wl*2+jl, bq) over K-half kh.
// B-frags (Whh rows) held in 96 VGPRs; A-frags read 16B/lane direct from bf16 ping-pong h-exchange.
__global__ __launch_bounds__(256, 1) void k_enc6(
    const bf16* __restrict__ Xg,
    const bf16* __restrict__ WB,     // [4][1536][512] bf16
    const float* __restrict__ b0, const float* __restrict__ b1,
    const float* __restrict__ b2, const float* __restrict__ b3,
    float* __restrict__ hh,          // [4][256][512][64] fp32
    bf16* __restrict__ hx,           // [2][4][64][512] bf16 ping-pong
    unsigned int* __restrict__ bar){
    int wg  = blockIdx.x;
    int grp = wg & 15;
    int wl  = wg >> 4;
    int dir = grp >> 2;
    int bq  = grp & 3;
    int tid = threadIdx.x;
    int lane = tid & 63;
    int wid = __builtin_amdgcn_readfirstlane(tid >> 6);
    int jl = wid & 1, kh = wid >> 1;
    int jt = wl*2 + jl;
    int ln = lane & 15, lk = lane >> 4;
    int j  = jt*16 + ln;
    int b0v = bq*16 + lk*4;
    const float* bhh = dir==0?b0:dir==1?b1:dir==2?b2:b3;
    const unsigned short* WBu = (const unsigned short*)WB;
    s8v Bf[3][8];
    #pragma unroll
    for (int g = 0; g < 3; ++g)
        #pragma unroll
        for (int q = 0; q < 8; ++q)
            Bf[g][q] = *(const s8v*)(WBu + ((size_t)(dir*NGE + g*512 + j))*512 + (kh*8+q)*32 + lk*8);
    float br=0.f, bz=0.f, bn=0.f;
    if (kh == 0){ br = bhh[j]; bz = bhh[j+512]; bn = bhh[j+1024]; }
    float hp0=0.f, hp1=0.f, hp2=0.f, hp3=0.f;
    __shared__ float red[2][3][64][4];
    unsigned int* gb = bar + grp*256;
    const unsigned short* Xgu = (const unsigned short*)Xg;
    for (int t = 0; t < NS; ++t){
        int tcur = (dir & 1) ? (255 - t) : t;
        f32x4 C0 = {0.f,0.f,0.f,0.f}, C1 = {0.f,0.f,0.f,0.f}, C2 = {0.f,0.f,0.f,0.f};
        ushort4 xr, xz, xn;
        if (kh == 0){
            size_t xb = (size_t)(dir*NS + tcur)*NGE;
            xr = *(const ushort4*)(Xgu + (xb + j)*NB + b0v);
            xz = *(const ushort4*)(Xgu + (xb + j + 512)*NB + b0v);
            xn = *(const ushort4*)(Xgu + (xb + j + 1024)*NB + b0v);
        }
        if (t > 0){
            const unsigned short* hxr = (const unsigned short*)hx
                + ((size_t)(((t-1)&1)*4 + dir)*64 + bq*16 + ln)*512 + kh*256 + lk*8;
            #pragma unroll
            for (int q = 0; q < 8; ++q){
                s8v Af = *(const s8v*)(hxr + q*32);
                C0 = __builtin_amdgcn_mfma_f32_16x16x32_bf16(Af, Bf[0][q], C0, 0, 0, 0);
                C1 = __builtin_amdgcn_mfma_f32_16x16x32_bf16(Af, Bf[1][q], C1, 0, 0, 0);
                C2 = __builtin_amdgcn_mfma_f32_16x16x32_bf16(Af, Bf[2][q], C2, 0, 0, 0);
            }
        }
        if (kh == 1){
            *(f32x4*)&red[jl][0][lane][0] = C0;
            *(f32x4*)&red[jl][1][lane][0] = C1;
            *(f32x4*)&red[jl][2][lane][0] = C2;
        }
        __syncthreads();
        if (kh == 0){
            C0 += *(const f32x4*)&red[jl][0][lane][0];
            C1 += *(const f32x4*)&red[jl][1][lane][0];
            C2 += *(const f32x4*)&red[jl][2][lane][0];
            {
                float r_ = sigmf(b2f(xr.x) + C0[0] + br);
                float z_ = sigmf(b2f(xz.x) + C1[0] + bz);
                float n_ = tanhf(b2f(xn.x) + r_*(C2[0] + bn));
                hp0 = (1.f - z_)*n_ + z_*hp0;
            }
            {
                float r_ = sigmf(b2f(xr.y) + C0[1] + br);
                float z_ = sigmf(b2f(xz.y) + C1[1] + bz);
                float n_ = tanhf(b2f(xn.y) + r_*(C2[1] + bn));
                hp1 = (1.f - z_)*n_ + z_*hp1;
            }
            {
                float r_ = sigmf(b2f(xr.z) + C0[2] + br);
                float z_ = sigmf(b2f(xz.z) + C1[2] + bz);
                float n_ = tanhf(b2f(xn.z) + r_*(C2[2] + bn));
                hp2 = (1.f - z_)*n_ + z_*hp2;
            }
            {
                float r_ = sigmf(b2f(xr.w) + C0[3] + br);
                float z_ = sigmf(b2f(xz.w) + C1[3] + bz);
                float n_ = tanhf(b2f(xn.w) + r_*(C2[3] + bn));
                hp3 = (1.f - z_)*n_ + z_*hp3;
            }
            f32x4 ho; ho[0] = hp0; ho[1] = hp1; ho[2] = hp2; ho[3] = hp3;
            *(f32x4*)(hh + ((size_t)(dir*NS + tcur)*NHE + j)*NB + b0v) = ho;
            bf16* hw = hx + ((size_t)((t&1)*4 + dir)*64)*512;
            hw[(size_t)(b0v+0)*512 + j] = __float2bfloat16(hp0);
            hw[(size_t)(b0v+1)*512 + j] = __float2bfloat16(hp1);
            hw[(size_t)(b0v+2)*512 + j] = __float2bfloat16(hp2);
            hw[(size_t)(b0v+3)*512 + j] = __float2bfloat16(hp3);
        }
        groupbar(gb, t+1, 2, wl);
    }
}

// decoder: 256 WGs x 256 thr (4 waves). group = bq = wg&3 (2 XCDs), jt = wg>>2 (0..63).
// wave wid = K-quarter (8 kt of 32). 3-way LDS reduce into wave 0, which does the gates.
__global__ __launch_bounds__(256, 1) void k_dec6(
    const bf16* __restrict__ MB,     // [3072][1024] bf16
    const float* __restrict__ cvec,
    const float* __restrict__ dbih,
    const bf16* __restrict__ Gctx,
    const bf16* __restrict__ ctxT,
    float* __restrict__ H,           // [256][1024][64] fp32
    bf16* __restrict__ Ht,           // [256][64][1024] bf16 history
    unsigned int* __restrict__ bar){
    int wg  = blockIdx.x;
    int grp = wg & 3;
    int jt  = wg >> 2;
    int tid = threadIdx.x;
    int lane = tid & 63;
    int wid = __builtin_amdgcn_readfirstlane(tid >> 6);
    int ln = lane & 15, lk = lane >> 4;
    int j  = jt*16 + ln;
    int b0v = grp*16 + lk*4;
    const unsigned short* MBu = (const unsigned short*)MB;
    s8v Bf[3][8];
    #pragma unroll
    for (int g = 0; g < 3; ++g)
        #pragma unroll
        for (int q = 0; q < 8; ++q)
            Bf[g][q] = *(const s8v*)(MBu + ((size_t)(g*NHD + j))*NHD + wid*256 + q*32 + lk*8);
    float c0=0.f,c1=0.f,c2=0.f,d0v=0.f,d1v=0.f,d2v=0.f;
    if (wid == 0){
        c0 = cvec[j]; c1 = cvec[j+NHD]; c2 = cvec[j+2*NHD];
        d0v = dbih[j]; d1v = dbih[j+NHD]; d2v = dbih[j+2*NHD];
    }
    __shared__ float red[3][3][64][4];
    unsigned int* gb = bar + grp*256;
    const unsigned short* Gu = (const unsigned short*)Gctx;
    const unsigned short* Cu = (const unsigned short*)ctxT;
    for (int i = 0; i < NS; ++i){
        f32x4 C0 = {0.f,0.f,0.f,0.f}, C1 = {0.f,0.f,0.f,0.f}, C2 = {0.f,0.f,0.f,0.f};
        ushort4 gr, gz, gn, cx;
        if (wid == 0){
            size_t gbx = (size_t)i*NGD*NB;
            gr = *(const ushort4*)(Gu + gbx + (size_t)j*NB + b0v);
            gz = *(const ushort4*)(Gu + gbx + (size_t)(j+NHD)*NB + b0v);
            gn = *(const ushort4*)(Gu + gbx + (size_t)(j+2*NHD)*NB + b0v);
            cx = *(const ushort4*)(Cu + ((size_t)i*NHD + j)*NB + b0v);
        }
        if (i > 0){
            const unsigned short* hxr = (const unsigned short*)Ht
                + ((size_t)(i-1)*NB + grp*16 + ln)*NHD + wid*256 + lk*8;
            #pragma unroll
            for (int q = 0; q < 8; ++q){
                s8v Af = *(const s8v*)(hxr + q*32);
                C0 = __builtin_amdgcn_mfma_f32_16x16x32_bf16(Af, Bf[0][q], C0, 0, 0, 0);
                C1 = __builtin_amdgcn_mfma_f32_16x16x32_bf16(Af, Bf[1][q], C1, 0, 0, 0);
                C2 = __builtin_amdgcn_mfma_f32_16x16x32_bf16(Af, Bf[2][q], C2, 0, 0, 0);
            }
        }
        if (wid != 0){
            *(f32x4*)&red[wid-1][0][lane][0] = C0;
            *(f32x4*)&red[wid-1][1][lane][0] = C1;
            *(f32x4*)&red[wid-1][2][lane][0] = C2;
        }
        __syncthreads();
        if (wid == 0){
            #pragma unroll
            for (int w = 0; w < 3; ++w){
                C0 += *(const f32x4*)&red[w][0][lane][0];
                C1 += *(const f32x4*)&red[w][1][lane][0];
                C2 += *(const f32x4*)&red[w][2][lane][0];
            }
            f32x4 ho;
            {
                float g0v = (i==0) ? d0v : C0[0] + c0;
                float g1v = (i==0) ? d1v : C1[0] + c1;
                float g2v = (i==0) ? d2v : C2[0] + c2;
                float r_ = sigmf(g0v + b2f(gr.x));
                float z_ = sigmf(g1v + b2f(gz.x));
                float n_ = tanhf(g2v + r_*b2f(gn.x));
                ho[0] = (1.f - z_)*n_ + z_*b2f(cx.x);
            }
            {
                float g0v = (i==0) ? d0v : C0[1] + c0;
                float g1v = (i==0) ? d1v : C1[1] + c1;
                float g2v = (i==0) ? d2v : C2[1] + c2;
                float r_ = sigmf(g0v + b2f(gr.y));
                float z_ = sigmf(g1v + b2f(gz.y));
                float n_ = tanhf(g2v + r_*b2f(gn.y));
                ho[1] = (1.f - z_)*n_ + z_*b2f(cx.y);
            }
            {
                float g0v = (i==0) ? d0v : C0[2] + c0;
                float g1v = (i==0) ? d1v : C1[2] + c1;
                float g2v = (i==0) ? d2v : C2[2] + c2;
                float r_ = sigmf(g0v + b2f(gr.z));
                float z_ = sigmf(g1v + b2f(gz.z));
                float n_ = tanhf(g2v + r_*b2f(gn.z));
                ho[2] = (1.f - z_)*n_ + z_*b2f(cx.z);
            }
            {
                float g0v = (i==0) ? d0v : C0[3] + c0;
                float g1v = (i==0) ? d1v : C1[3] + c1;
                float g2v = (i==0) ? d2v : C2[3] + c2;
                float r_ = sigmf(g0v + b2f(gr.w));
                float z_ = sigmf(g1v + b2f(gz.w));
                float n_ = tanhf(g2v + r_*b2f(gn.w));
                ho[3] = (1.f - z_)*n_ + z_*b2f(cx.w);
            }
            *(f32x4*)(H + ((size_t)i*NHD + j)*NB + b0v) = ho;
            Ht[((size_t)i*NB + b0v+0)*NHD + j] = __float2bfloat16(ho[0]);
            Ht[((size_t)i*NB + b0v+1)*NHD + j] = __float2bfloat16(ho[1]);
            Ht[((size_t)i*NB + b0v+2)*NHD + j] = __float2bfloat16(ho[2]);
            Ht[((size_t)i*NB + b0v+3)*NHD + j] = __float2bfloat16(ho[3]);
        }
        groupbar(gb, i+1, 8, jt);
    }
}

// ---------------- host launcher ----------------
extern "C" void kernel_launch(void* const* d_in, const int* in_sizes, int n_in,
                              void* d_out, int out_size, void* d_ws, size_t ws_size,
                              hipStream_t stream){
    const float* x   = (const float*)d_in[0];
    const float* eps = (const float*)d_in[1];
    const float* Wih[4]; const float* Whh[4]; const float* bih[4]; const float* bhh[4];
    for (int d = 0; d < 4; ++d){
        Wih[d] = (const float*)d_in[2 + 4*d];
        Whh[d] = (const float*)d_in[3 + 4*d];
        bih[d] = (const float*)d_in[4 + 4*d];
        bhh[d] = (const float*)d_in[5 + 4*d];
    }
    const float* dWih  = (const float*)d_in[18];
    const float* dWhh  = (const float*)d_in[19];
    const float* dbih  = (const float*)d_in[20];
    const float* dbhh  = (const float*)d_in[21];
    const float* attnW = (const float*)d_in[22];
    const float* attnb = (const float*)d_in[23];
    const float* linW  = (const float*)d_in[24];
    const float* linb  = (const float*)d_in[25];

    float* out    = (float*)d_out;
    float* outRec = out;
    float* outMu  = out + 8388608;
    float* outLv  = out + 25165824;

    char* ws = (char*)d_ws;
    bf16*  Xg    = (bf16*)(ws + 0);              // 201326592 (dead after encoder)
    bf16*  Gctx  = (bf16*)(ws + 0);              // 100663296 (reuses Xg)
    float* Hdec  = (float*)(ws + 100663296);     // 67108864  (reuses Xg)
    float* hh    = (float*)(ws + 201326592);     // 134217728
    bf16*  zbuf  = (bf16*)(ws + 335544320);      // 33554432
    bf16*  ctxT  = (bf16*)(ws + 369098752);      // 33554432
    bf16*  MbufB = (bf16*)(ws + 402653184);      // 6291456
    bf16*  WhhB  = (bf16*)(ws + 408944640);      // 6291456
    bf16*  Ht    = (bf16*)(ws + 415236096);      // 33554432
    float* sx    = (float*)(ws + 448790528);     // 65536
    float* esb   = (float*)(ws + 448856064);     // 65536
    float* Se    = (float*)(ws + 448921600);     // 4096
    float* Tbuf  = (float*)(ws + 448925696);     // 262144
    float* cvec  = (float*)(ws + 449187840);     // 12288
    unsigned int* barE = (unsigned int*)(ws + 449200128);  // 16384
    unsigned int* barD = (unsigned int*)(ws + 449216512);  // 16384
    bf16*  hxb   = (bf16*)(ws + 449232896);      // 524288 bf16 ping-pong h-exchange

    hipMemsetAsync(ws + 449200128, 0, 32768, stream);

    // phase 0: parallel prep
    hipLaunchKernelGGL(k_gemm_M, dim3(48,16), dim3(256), 0, stream, dWih, linW, MbufB);
    for (int d = 0; d < 4; ++d)
        hipLaunchKernelGGL(k_cvtW, dim3(768), dim3(256), 0, stream, Whh[d], WhhB + (size_t)d*NGE*NHE);
    hipLaunchKernelGGL(k_cvec, dim3(768), dim3(256), 0, stream, dWih, linb, dbih, cvec);
    hipLaunchKernelGGL(k_sx, dim3(4096), dim3(256), 0, stream, x, attnW, attnb, sx);
    hipLaunchKernelGGL(k_softprep2, dim3(64), dim3(256), 0, stream, sx, esb, Se);
    hipLaunchKernelGGL(k_gemm_xg, dim3(256,24,4), dim3(256), 0, stream,
                       x, Wih[0], Wih[1], Wih[2], Wih[3], bih[0], bih[1], bih[2], bih[3], Xg);

    // phase 1: encoder recurrence (MFMA) -> hh
    {
        void* a[] = { (void*)&Xg, (void*)&WhhB,
                      (void*)&bhh[0], (void*)&bhh[1], (void*)&bhh[2], (void*)&bhh[3],
                      (void*)&hh, (void*)&hxb, (void*)&barE };
        hipLaunchCooperativeKernel((void*)k_enc6, dim3(256), dim3(256), a, 0, stream);
    }

    // phase 2: z, attention statics, Gctx; mu/logvar output transpose
    hipLaunchKernelGGL(k_zexp2, dim3(4096), dim3(256), 0, stream, hh, eps, zbuf);
    hipLaunchKernelGGL(k_outT, dim3(8192), dim3(256), 0, stream, hh, outMu, outLv);
    hipLaunchKernelGGL(k_T2, dim3(1024), dim3(256), 0, stream, zbuf, esb, Tbuf);
    hipLaunchKernelGGL(k_ctx2, dim3(4096), dim3(256), 0, stream, zbuf, esb, Se, Tbuf, ctxT);
    hipLaunchKernelGGL(k_gemm_gctx, dim3(256,48), dim3(256), 0, stream, ctxT, dWhh, dbhh, Gctx);

    // phase 3: decoder recurrence (MFMA)
    {
        void* a[] = { (void*)&MbufB, (void*)&cvec, (void*)&dbih, (void*)&Gctx, (void*)&ctxT,
                      (void*)&Hdec, (void*)&Ht, (void*)&barD };
        hipLaunchCooperativeKernel((void*)k_dec6, dim3(256), dim3(256), a, 0, stream);
    }

    // phase 4: output projection
    hipLaunchKernelGGL(k_gemm_rec, dim3(256,8), dim3(256), 0, stream, Hdec, linW, linb, outRec);
}